// Round 6
// baseline (610.618 us; speedup 1.0000x reference)
//
#include <hip/hip_runtime.h>

#define N_ 100000
#define D_ 128
#define O_ 128
#define V_ 3
#define E_ 400000
#define NB_SCAN 98   // ceil(N/1024)
#define EGRID 1563   // ceil(E/256)
#define MB 64        // nodes per k_fused block
#define NBLK 1563    // ceil(N/64); last block has 32 valid rows
#define LDA 136      // padded bf16 row stride (16B-aligned)

// fused pre-kernel block ranges
#define PRE_CVT  6250                   // feature cvt (f32 path only)
#define PRE_PREW (PRE_CVT + 64)         // 6314
#define PRE_PREP (PRE_PREW + 617)       // 6931
#define PRE_TOT  (PRE_PREP + 3 * EGRID) // 11620

typedef unsigned short u16;
typedef __attribute__((ext_vector_type(8))) short bf16x8;   // 8 bf16 = 4 VGPRs
typedef __attribute__((ext_vector_type(4))) float f32x4;

#define MFMA16x16x32 __builtin_amdgcn_mfma_f32_16x16x32_bf16

// ---- fp32 param block offsets (in workspace, filled by prep) ----
#define P_RELB  0
#define P_GATEB 384
#define P_VP    768
#define P_VAB1  1152
#define P_VAW2  1216
#define P_VAB2  1280
#define P_LAB1  1281
#define P_LAW2  1409
#define P_LAB2  1537
#define P_PREDB 1539
#define P_ATTB  1541
#define P_FTB   1542
#define P_LNG   1670
#define P_LNB   1798
#define P_PREDW 1926
#define P_TOTAL 2182

__device__ __forceinline__ float b2f(u16 u) {
    union { float f; unsigned int i; } x; x.i = ((unsigned int)u) << 16; return x.f;
}
__device__ __forceinline__ float blo(unsigned int u) {
    union { float f; unsigned int i; } x; x.i = u << 16; return x.f;
}
__device__ __forceinline__ float bhi(unsigned int u) {
    union { float f; unsigned int i; } x; x.i = u & 0xffff0000u; return x.f;
}
__device__ __forceinline__ u16 f2b(float f) {
    union { float f; unsigned int i; } x; x.f = f;
    unsigned int r = x.i + 0x7FFFu + ((x.i >> 16) & 1u);
    return (u16)(r >> 16);
}

template<int F32> __device__ __forceinline__ float LD(const void* p, size_t i) {
    if (F32) return ((const float*)p)[i];
    return b2f(((const u16*)p)[i]);
}

// ---------------- dtype detector: fp32 vs bf16 element stream ----------------
__global__ void k_detect(const u16* __restrict__ feat, int* __restrict__ flag) {
    int t = threadIdx.x;   // 64 lanes; check feat[2i], i = t and t+64
    u16 a = feat[2 * t], b = feat[2 * t + 128];
    int zeros = (a == 0 ? 1 : 0) + (b == 0 ? 1 : 0);
    float va = b2f(a), vb = b2f(b);
    int bad = (!(va > -128.f && va < 128.f) ? 1 : 0) +
              (!(vb > -128.f && vb < 128.f) ? 1 : 0);
    #pragma unroll
    for (int s = 1; s <= 32; s <<= 1) {
        bad += __shfl_xor(bad, s);
        zeros += __shfl_xor(zeros, s);
    }
    if (t == 0) flag[0] = (bad >= 16 || zeros >= 64) ? 1 : 0;
}

// ---------------- fused pre kernel: cvt | prew | prep | count ----------------
__device__ __forceinline__ void cvt_body_f32(int b, const void* feat,
                                             u16* __restrict__ featB) {
    size_t idx = (size_t)b * 256 + threadIdx.x;   // 8 elems per thread
    const float4* fp = (const float4*)feat;
    float4 a = fp[idx * 2], c = fp[idx * 2 + 1];
    uint4 u;
    u.x = (unsigned)f2b(a.x) | ((unsigned)f2b(a.y) << 16);
    u.y = (unsigned)f2b(a.z) | ((unsigned)f2b(a.w) << 16);
    u.z = (unsigned)f2b(c.x) | ((unsigned)f2b(c.y) << 16);
    u.w = (unsigned)f2b(c.z) | ((unsigned)f2b(c.w) << 16);
    ((uint4*)featB)[idx] = u;
}

template<int F32>
__device__ __forceinline__ void prew_body(int b, const void* sl_w, const void* sl_b,
                                          const void* fus_w, const void* fus_b,
                                          u16* __restrict__ W1T, float* __restrict__ b1) {
    int gid = b * 256 + threadIdx.x;   // 64 blocks
    int d = gid >> 7, o = gid & 127;
    float acc = 0.f;
    for (int k = 0; k < 128; ++k)
        acc += LD<F32>(sl_w, d * 128 + k) * LD<F32>(fus_w, k * 128 + o);
    W1T[o * 128 + d] = f2b(acc);
    if (gid < 128) {
        float accb = 0.f;
        for (int k = 0; k < 128; ++k)
            accb += LD<F32>(sl_b, k) * LD<F32>(fus_w, k * 128 + gid);
        b1[gid] = accb + LD<F32>(fus_b, gid);
    }
}

template<int F32>
__device__ __forceinline__ void prep_body(int b,
        const void* rel_w, const void* gate_w, const void* va_w1, const void* fus_w,
        const void* ft_w, const void* la_w1,
        const void* rel_b, const void* gate_b, const void* vpref,
        const void* va_b1, const void* va_w2, const void* va_b2,
        const void* la_b1, const void* la_w2, const void* la_b2,
        const void* pred_b, const void* att_bias, const void* ft_b,
        const void* ln_g, const void* ln_beta, const void* pred_w,
        u16* __restrict__ relT, u16* __restrict__ gateT, u16* __restrict__ vaT,
        u16* __restrict__ fus2T, u16* __restrict__ ftT, u16* __restrict__ laT,
        float* __restrict__ P) {
    int id = b * 256 + threadIdx.x;
    if (id < 49152) {
        int v = id >> 14, r = id & 16383, o = r >> 7, d = r & 127;
        relT[id] = f2b(LD<F32>(rel_w, (size_t)v * 16384 + d * 128 + o));
    } else if (id < 98304) {
        int t = id - 49152, v = t >> 14, r = t & 16383, o = r >> 7, d = r & 127;
        gateT[t] = f2b(LD<F32>(gate_w, (size_t)v * 16384 + d * 128 + o));
    } else if (id < 106496) {
        int t = id - 98304, n = t >> 7, k = t & 127;
        vaT[t] = f2b(LD<F32>(va_w1, k * 64 + n));
    } else if (id < 122880) {
        int t = id - 106496, n = t >> 7, k = t & 127;
        fus2T[t] = f2b(LD<F32>(fus_w, (128 + k) * 128 + n));
    } else if (id < 139264) {
        int t = id - 122880, o = t >> 7, d = t & 127;
        ftT[t] = f2b(LD<F32>(ft_w, d * 128 + o));
    } else if (id < 155648) {
        int t = id - 139264, n = t >> 7, d = t & 127;
        int c = n >> 6, j = n & 63;
        laT[t] = f2b(LD<F32>(la_w1, c * 8192 + d * 64 + j));
    } else if (id < 155648 + P_TOTAL) {
        int t = id - 155648;
        float val;
        if      (t < P_GATEB) val = LD<F32>(rel_b, t);
        else if (t < P_VP)    val = LD<F32>(gate_b, t - P_GATEB);
        else if (t < P_VAB1)  val = LD<F32>(vpref, t - P_VP);
        else if (t < P_VAW2)  val = LD<F32>(va_b1, t - P_VAB1);
        else if (t < P_VAB2)  val = LD<F32>(va_w2, t - P_VAW2);
        else if (t < P_LAB1)  val = LD<F32>(va_b2, 0);
        else if (t < P_LAW2)  val = LD<F32>(la_b1, t - P_LAB1);
        else if (t < P_LAB2)  val = LD<F32>(la_w2, t - P_LAW2);
        else if (t < P_PREDB) val = LD<F32>(la_b2, t - P_LAB2);
        else if (t < P_ATTB)  val = LD<F32>(pred_b, t - P_PREDB);
        else if (t < P_FTB)   val = LD<F32>(att_bias, 0);
        else if (t < P_LNG)   val = LD<F32>(ft_b, t - P_FTB);
        else if (t < P_LNB)   val = LD<F32>(ln_g, t - P_LNG);
        else if (t < P_PREDW) val = LD<F32>(ln_beta, t - P_LNB);
        else                  val = LD<F32>(pred_w, t - P_PREDW);
        P[t] = val;
    }
}

__global__ __launch_bounds__(256) void k_preC(const int* __restrict__ flag,
        const void* feat, u16* __restrict__ featB,
        const void* sl_w, const void* sl_b, const void* fus_w, const void* fus_b,
        u16* __restrict__ W1T, float* __restrict__ b1,
        const void* rel_w, const void* gate_w, const void* va_w1,
        const void* ft_w, const void* la_w1,
        const void* rel_b, const void* gate_b, const void* vpref,
        const void* va_b1, const void* va_w2, const void* va_b2,
        const void* la_b1, const void* la_w2, const void* la_b2,
        const void* pred_b, const void* att_bias, const void* ft_b,
        const void* ln_g, const void* ln_beta, const void* pred_w,
        u16* __restrict__ relT, u16* __restrict__ gateT, u16* __restrict__ vaT,
        u16* __restrict__ fus2T, u16* __restrict__ ftT, u16* __restrict__ laT,
        float* __restrict__ P,
        const int* __restrict__ ei, int* __restrict__ cur3) {
    int b = blockIdx.x;
    if (b < PRE_CVT) {
        if (flag[0]) cvt_body_f32(b, feat, featB);   // bf16 case: featB unused
    } else if (b < PRE_PREW) {
        if (flag[0]) prew_body<1>(b - PRE_CVT, sl_w, sl_b, fus_w, fus_b, W1T, b1);
        else         prew_body<0>(b - PRE_CVT, sl_w, sl_b, fus_w, fus_b, W1T, b1);
    } else if (b < PRE_PREP) {
        if (flag[0]) prep_body<1>(b - PRE_PREW, rel_w, gate_w, va_w1, fus_w, ft_w, la_w1,
                                  rel_b, gate_b, vpref, va_b1, va_w2, va_b2,
                                  la_b1, la_w2, la_b2, pred_b, att_bias, ft_b,
                                  ln_g, ln_beta, pred_w, relT, gateT, vaT, fus2T, ftT, laT, P);
        else         prep_body<0>(b - PRE_PREW, rel_w, gate_w, va_w1, fus_w, ft_w, la_w1,
                                  rel_b, gate_b, vpref, va_b1, va_w2, va_b2,
                                  la_b1, la_w2, la_b2, pred_b, att_bias, ft_b,
                                  ln_g, ln_beta, pred_w, relT, gateT, vaT, fus2T, ftT, laT, P);
    } else {
        int b2 = b - PRE_PREP;
        int v = b2 / EGRID;
        int e = (b2 % EGRID) * 256 + threadIdx.x;
        if (e < E_) atomicAdd(&cur3[v * N_ + ei[(size_t)v * 2 * E_ + E_ + e]], 1);
    }
}

// ---------------- CSR scan: bsum / write (inline spine) ----------------------
__global__ __launch_bounds__(256) void k_scan_bsum(const int* __restrict__ cur3,
                                                   int* __restrict__ bsum) {
    __shared__ int red[256];
    const int v = blockIdx.x / NB_SCAN, b = blockIdx.x % NB_SCAN, tid = threadIdx.x;
    const int base = b * 1024;
    const int* counts = cur3 + v * N_;
    int s = 0;
    for (int i = tid; i < 1024; i += 256) {
        int idx = base + i;
        s += (idx < N_) ? counts[idx] : 0;
    }
    red[tid] = s;
    __syncthreads();
    for (int st = 128; st >= 1; st >>= 1) {
        if (tid < st) red[tid] += red[tid + st];
        __syncthreads();
    }
    if (tid == 0) bsum[v * 128 + b] = red[0];
}

__global__ __launch_bounds__(256) void k_scan_write(int* __restrict__ cur3,
                                                    const int* __restrict__ bsum,
                                                    int* __restrict__ offs3) {
    __shared__ int lsum[256];
    __shared__ int bs_s[128];
    const int v = blockIdx.x / NB_SCAN, b = blockIdx.x % NB_SCAN, tid = threadIdx.x;
    const int base = b * 1024;
    int* counts = cur3 + v * N_;
    int* offs   = offs3 + v * N_;
    if (tid < 128) bs_s[tid] = (tid < b) ? bsum[v * 128 + tid] : 0;
    int c[4]; int s = 0;
    #pragma unroll
    for (int k = 0; k < 4; ++k) {
        int idx = base + tid * 4 + k;
        c[k] = (idx < N_) ? counts[idx] : 0;
        s += c[k];
    }
    lsum[tid] = s;
    __syncthreads();
    for (int st = 1; st < 256; st <<= 1) {
        int t = (tid >= st) ? lsum[tid - st] : 0;
        __syncthreads();
        lsum[tid] += t;
        __syncthreads();
    }
    for (int st = 64; st >= 1; st >>= 1) {
        if (tid < st) bs_s[tid] += bs_s[tid + st];
        __syncthreads();
    }
    int off = bs_s[0] + lsum[tid] - s;
    #pragma unroll
    for (int k = 0; k < 4; ++k) {
        int idx = base + tid * 4 + k;
        if (idx < N_) { offs[idx] = off; counts[idx] = off; }
        off += c[k];
    }
}

// place: srcw[pos] = {src, weight-bits}
template<int F32>
__device__ __forceinline__ void place_body(const int* __restrict__ ei, const void* ew_all,
                                           int* __restrict__ cur3, int2* __restrict__ srcw3) {
    int v = blockIdx.x / EGRID;
    int e = (blockIdx.x % EGRID) * 256 + threadIdx.x;
    if (e < E_) {
        int dst = ei[(size_t)v * 2 * E_ + E_ + e];
        int src = ei[(size_t)v * 2 * E_ + e];
        float w = LD<F32>(ew_all, (size_t)v * E_ + e);
        int pos = atomicAdd(&cur3[v * N_ + dst], 1);
        int2 sw; sw.x = src; sw.y = __float_as_int(w);
        srcw3[(size_t)v * E_ + pos] = sw;
    }
    // afterwards cur3[v*N+n] == row end
}
__global__ __launch_bounds__(256) void k_place(const int* __restrict__ flag,
                                               const int* __restrict__ ei, const void* ew,
                                               int* __restrict__ cur3, int2* __restrict__ srcw3) {
    if (flag[0]) place_body<1>(ei, ew, cur3, srcw3);
    else         place_body<0>(ei, ew, cur3, srcw3);
}

// ------ fused MFMA pipeline: MB=64, 768 threads, view-parallel groups --------
// Group g (4 waves) owns view g. LDS pool 69.6KB (xA|zb0|zb1|zb2) with f32
// overlays F1 (zb1+zb2, after combine) and F2 (xA+zb0, after B9).
// Total LDS ~78 KB -> 2 blocks/CU = 24 waves; rounds 3125->1563 blocks.
__global__ __launch_bounds__(768, 6) void k_fused(const int* __restrict__ flag,
        const void* feat, const u16* __restrict__ featB_,
        const int2* __restrict__ srcw3,
        const int* __restrict__ offs3, const int* __restrict__ ends3,
        const u16* __restrict__ relT, const u16* __restrict__ gateT,
        const u16* __restrict__ vaT, const u16* __restrict__ W1T,
        const u16* __restrict__ fus2T, const u16* __restrict__ ftT,
        const u16* __restrict__ laT,
        const float* __restrict__ b1, const float* __restrict__ P,
        void* __restrict__ d_out) {
    const int f32 = flag[0];
    const u16* __restrict__ fb = f32 ? featB_ : (const u16*)feat;

    __shared__ __align__(16) u16 S[4 * MB * LDA];     // xA | zb0 | zb1 | zb2
    __shared__ float vp3_s[3][128];
    __shared__ float redL[4][MB];
    __shared__ float redv[3][4][MB];                  // va reduce; overlay LN red2
    __shared__ float wsn3[3][MB];
    __shared__ float aw_s[MB][3];
    __shared__ float natt_s[MB];
    __shared__ float lg_s[MB][2];
    __shared__ float mrs_s[MB][2];

    u16* xA = S;
    float* F1 = (float*)(S + 2 * MB * LDA);   // 32KB over zb1+zb2
    float* F2 = (float*)S;                    // 32KB over xA+zb0
    float* red2 = &redv[0][0][0];             // [4][MB][2] overlay (512 f32)

    const int tid = threadIdx.x;
    const int g   = tid >> 8;               // wave-group / view 0..2
    const int t256 = tid & 255;
    const int wid = t256 >> 6;              // wave within group 0..3
    const int L = t256 & 63, q = L >> 4, i = L & 15;
    const int nb = wid * 32;
    const int nodebase = blockIdx.x * MB;
    const int nl = t256 >> 5, l32 = t256 & 31, o4 = l32 * 4;
    const int gsub = t256 >> 4, l16 = tid & 15, o8 = l16 * 8;
    const f32x4 zz = {0.f, 0.f, 0.f, 0.f};
    u16* zc = S + (size_t)(1 + g) * MB * LDA;   // this group's z buffer

    auto ldf = [&](const u16* B, int row, int k0) -> bf16x8 {
        return *(const bf16x8*)&B[row * LDA + k0];
    };
    auto ldg = [&](const u16* B, int row, int k0) -> bf16x8 {
        return *(const bf16x8*)&B[row * 128 + k0];
    };
    // M=64 gemm by the 4 waves of one group: acc[mt][nt], rows mt*16+q*4+r
    auto gemm64 = [&](const u16* A, const u16* Bg, f32x4 acc[4][2]) {
        #pragma unroll
        for (int kk = 0; kk < 4; ++kk) {
            int k0 = q * 8 + kk * 32;
            bf16x8 bb0 = ldg(Bg, nb + i, k0);
            bf16x8 bb1 = ldg(Bg, nb + 16 + i, k0);
            #pragma unroll
            for (int mt = 0; mt < 4; ++mt) {
                bf16x8 a = ldf(A, i + mt * 16, k0);
                acc[mt][0] = MFMA16x16x32(a, bb0, acc[mt][0], 0, 0, 0);
                acc[mt][1] = MFMA16x16x32(a, bb1, acc[mt][1], 0, 0, 0);
            }
        }
    };
    // gather view g: 16 subgroups of 16 lanes; 4 nodes per subgroup
    auto gather = [&]() {
        const int* offs = offs3 + g * N_;
        const int* ends = ends3 + g * N_;
        const int2* srcw = srcw3 + (size_t)g * E_;
        #pragma unroll
        for (int rep = 0; rep < 4; ++rep) {
            const int m = gsub + rep * 16;
            const int node = nodebase + m;
            if (node < N_) {
                float z0 = 0.f, z1 = 0.f, z2 = 0.f, z3 = 0.f;
                float z4 = 0.f, z5 = 0.f, z6 = 0.f, z7 = 0.f, ws = 0.f;
                int j = offs[node], jend = ends[node];
                while (j < jend) {
                    int r = jend - j;
                    int2 e0 = srcw[j];
                    int2 e1, e2, e3;
                    e1.x = 0; e1.y = 0; e2.x = 0; e2.y = 0; e3.x = 0; e3.y = 0;
                    if (r > 1) e1 = srcw[j + 1];
                    if (r > 2) e2 = srcw[j + 2];
                    if (r > 3) e3 = srcw[j + 3];
                    uint4 x0, x1, x2, x3;
                    x1.x = x1.y = x1.z = x1.w = 0;
                    x2.x = x2.y = x2.z = x2.w = 0;
                    x3.x = x3.y = x3.z = x3.w = 0;
                    x0 = *(const uint4*)&fb[(size_t)e0.x * 128 + o8];
                    if (r > 1) x1 = *(const uint4*)&fb[(size_t)e1.x * 128 + o8];
                    if (r > 2) x2 = *(const uint4*)&fb[(size_t)e2.x * 128 + o8];
                    if (r > 3) x3 = *(const uint4*)&fb[(size_t)e3.x * 128 + o8];
                    float w0 = __int_as_float(e0.y), w1 = __int_as_float(e1.y);
                    float w2 = __int_as_float(e2.y), w3 = __int_as_float(e3.y);
                    ws += w0 + w1 + w2 + w3;
                    z0 += w0 * blo(x0.x) + w1 * blo(x1.x) + w2 * blo(x2.x) + w3 * blo(x3.x);
                    z1 += w0 * bhi(x0.x) + w1 * bhi(x1.x) + w2 * bhi(x2.x) + w3 * bhi(x3.x);
                    z2 += w0 * blo(x0.y) + w1 * blo(x1.y) + w2 * blo(x2.y) + w3 * blo(x3.y);
                    z3 += w0 * bhi(x0.y) + w1 * bhi(x1.y) + w2 * bhi(x2.y) + w3 * bhi(x3.y);
                    z4 += w0 * blo(x0.z) + w1 * blo(x1.z) + w2 * blo(x2.z) + w3 * blo(x3.z);
                    z5 += w0 * bhi(x0.z) + w1 * bhi(x1.z) + w2 * bhi(x2.z) + w3 * bhi(x3.z);
                    z6 += w0 * blo(x0.w) + w1 * blo(x1.w) + w2 * blo(x2.w) + w3 * blo(x3.w);
                    z7 += w0 * bhi(x0.w) + w1 * bhi(x1.w) + w2 * bhi(x2.w) + w3 * bhi(x3.w);
                    j += 4;
                }
                uint4 u;
                u.x = (unsigned)f2b(z0) | ((unsigned)f2b(z1) << 16);
                u.y = (unsigned)f2b(z2) | ((unsigned)f2b(z3) << 16);
                u.z = (unsigned)f2b(z4) | ((unsigned)f2b(z5) << 16);
                u.w = (unsigned)f2b(z6) | ((unsigned)f2b(z7) << 16);
                *(uint4*)&zc[m * LDA + o8] = u;
                if (l16 == 0) wsn3[g][m] = ws;
            }
        }
    };

    // ---- P0: stage xA (zero-pad tail rows) + vp; each group gathers ----
    for (int idx = tid; idx < MB * 16; idx += 768) {
        int m = idx >> 4, s = idx & 15;
        int node = nodebase + m;
        uint4 u; u.x = 0; u.y = 0; u.z = 0; u.w = 0;
        if (node < N_) u = *(const uint4*)&fb[(size_t)node * 128 + s * 8];
        *(uint4*)&xA[m * LDA + s * 8] = u;
    }
    if (tid >= 256 && tid < 640) {  // vp3: 384 floats
        int t = tid - 256;
        vp3_s[t >> 7][t & 127] = P[P_VP + t];
    }
    gather();
    __syncthreads();                                               // B1

    // ---- P1: g0 does label-attention FIRST (frees accL), then all rel gemms --
    if (g == 0) {
        f32x4 accL[4][2] = {{zz, zz}, {zz, zz}, {zz, zz}, {zz, zz}};
        gemm64(xA, laT, accL);
        float pw[8];
        #pragma unroll
        for (int t = 0; t < 4; ++t) {
            pw[2 * t]     = P[P_PREDW + (o4 + t) * 2];
            pw[2 * t + 1] = P[P_PREDW + (o4 + t) * 2 + 1];
        }
        #pragma unroll
        for (int rep = 0; rep < 8; ++rep) {
            int m = rep * 8 + nl;
            float lg0 = 0.f, lg1 = 0.f;
            #pragma unroll
            for (int t = 0; t < 4; ++t) {
                float xv = b2f(xA[m * LDA + o4 + t]);
                lg0 += xv * pw[2 * t];
                lg1 += xv * pw[2 * t + 1];
            }
            #pragma unroll
            for (int s = 1; s <= 16; s <<= 1) {
                lg0 += __shfl_xor(lg0, s);
                lg1 += __shfl_xor(lg1, s);
            }
            if (l32 == 0) { lg_s[m][0] = lg0; lg_s[m][1] = lg1; }
        }
        float la0 = P[P_LAB1 + nb + i],  la1 = P[P_LAB1 + nb + 16 + i];
        float lw0 = P[P_LAW2 + nb + i],  lw1 = P[P_LAW2 + nb + 16 + i];
        #pragma unroll
        for (int mt = 0; mt < 4; ++mt) {
            float partL[4];
            #pragma unroll
            for (int r = 0; r < 4; ++r) {
                float h0 = fmaxf(accL[mt][0][r] + la0, 0.f);
                float h1 = fmaxf(accL[mt][1][r] + la1, 0.f);
                partL[r] = h0 * lw0 + h1 * lw1;
            }
            #pragma unroll
            for (int s = 1; s <= 8; s <<= 1)
                #pragma unroll
                for (int r = 0; r < 4; ++r)
                    partL[r] += __shfl_xor(partL[r], s);
            if (i == 0)
                #pragma unroll
                for (int r = 0; r < 4; ++r)
                    redL[wid][mt * 16 + q * 4 + r] = partL[r];
        }
    }
    f32x4 accA[4][2] = {{zz, zz}, {zz, zz}, {zz, zz}, {zz, zz}};
    gemm64(zc, relT + (size_t)g * 16384, accA);
    __syncthreads();                                               // B2

    // ---- P2: agg = acc + wsn*rel_b -> zc; natt (tid<64) ----
    {
        float rb0 = P[P_RELB + g * 128 + nb + i];
        float rb1 = P[P_RELB + g * 128 + nb + 16 + i];
        #pragma unroll
        for (int mt = 0; mt < 4; ++mt)
            #pragma unroll
            for (int nt = 0; nt < 2; ++nt) {
                float rb = nt ? rb1 : rb0;
                int col = nb + nt * 16 + i;
                #pragma unroll
                for (int r = 0; r < 4; ++r) {
                    int row = mt * 16 + q * 4 + r;
                    float a = accA[mt][nt][r] + wsn3[g][row] * rb;
                    accA[mt][nt][r] = a;
                    zc[row * LDA + col] = f2b(a);
                }
            }
    }
    if (tid < MB) {
        float c0 = redL[0][tid] + redL[1][tid] + P[P_LAB2 + 0];
        float c1 = redL[2][tid] + redL[3][tid] + P[P_LAB2 + 1];
        float s0 = 1.f / (1.f + __expf(-c0));
        float s1 = 1.f / (1.f + __expf(-c1));
        float l0 = lg_s[tid][0] + P[P_PREDB + 0];
        float l1 = lg_s[tid][1] + P[P_PREDB + 1];
        float mx = fmaxf(l0, l1);
        float e0 = __expf(l0 - mx), e1 = __expf(l1 - mx);
        float inv = 1.f / (e0 + e1);
        float p0 = e0 * inv, p1 = e1 * inv;
        natt_s[tid] = s0 * p0 + s1 * p1 + P[P_ATTB];
        int node = nodebase + tid;
        if (node < N_) {
            if (f32) {
                float* pr = (float*)d_out + (size_t)N_ * O_;
                pr[node * 2 + 0] = p0; pr[node * 2 + 1] = p1;
            } else {
                u16* pr = (u16*)d_out + (size_t)N_ * O_;
                pr[node * 2 + 0] = f2b(p0); pr[node * 2 + 1] = f2b(p1);
            }
        }
    }
    __syncthreads();                                               // B3

    // ---- P3: gate gemm ----
    f32x4 acc2[4][2] = {{zz, zz}, {zz, zz}, {zz, zz}, {zz, zz}};
    gemm64(zc, gateT + (size_t)g * 16384, acc2);
    __syncthreads();                                               // B4

    // ---- P4: vv = sigmoid(acc2+gb)*agg -> zc ----
    {
        float gb0 = P[P_GATEB + g * 128 + nb + i];
        float gb1 = P[P_GATEB + g * 128 + nb + 16 + i];
        #pragma unroll
        for (int mt = 0; mt < 4; ++mt)
            #pragma unroll
            for (int nt = 0; nt < 2; ++nt) {
                float gb = nt ? gb1 : gb0;
                int col = nb + nt * 16 + i;
                #pragma unroll
                for (int r = 0; r < 4; ++r) {
                    int row = mt * 16 + q * 4 + r;
                    float gt = 1.f / (1.f + __expf(-(acc2[mt][nt][r] + gb)));
                    zc[row * LDA + col] = f2b(gt * accA[mt][nt][r]);
                }
            }
    }
    __syncthreads();                                               // B5

    // ---- P5: va gemm on pe = vv*vp (vp folded into A-frag) ----
    {
        f32x4 accV[4] = {zz, zz, zz, zz};
        const int nbv = wid * 16, colv = nbv + i;
        #pragma unroll
        for (int kk = 0; kk < 4; ++kk) {
            int k0 = q * 8 + kk * 32;
            bf16x8 bb = ldg(vaT, nbv + i, k0);
            #pragma unroll
            for (int mt = 0; mt < 4; ++mt) {
                bf16x8 ar = ldf(zc, i + mt * 16, k0);
                bf16x8 a;
                #pragma unroll
                for (int e = 0; e < 8; ++e)
                    a[e] = (short)f2b(b2f((u16)ar[e]) * vp3_s[g][k0 + e]);
                accV[mt] = MFMA16x16x32(a, bb, accV[mt], 0, 0, 0);
            }
        }
        float vb1v = P[P_VAB1 + colv], vw2v = P[P_VAW2 + colv];
        #pragma unroll
        for (int mt = 0; mt < 4; ++mt) {
            float part[4];
            #pragma unroll
            for (int r = 0; r < 4; ++r) {
                float vh = fmaxf(accV[mt][r] + vb1v, 0.f);
                part[r] = vh * vw2v;
            }
            #pragma unroll
            for (int s = 1; s <= 8; s <<= 1)
                #pragma unroll
                for (int r = 0; r < 4; ++r)
                    part[r] += __shfl_xor(part[r], s);
            if (i == 0)
                #pragma unroll
                for (int r = 0; r < 4; ++r)
                    redv[g][wid][mt * 16 + q * 4 + r] = part[r];
        }
    }
    __syncthreads();                                               // B6

    // ---- P6: vscore + view softmax * natt (tid<64) ----
    if (tid < MB) {
        float sv[3];
        #pragma unroll
        for (int v = 0; v < 3; ++v)
            sv[v] = redv[v][0][tid] + redv[v][1][tid] +
                    redv[v][2][tid] + redv[v][3][tid] + P[P_VAB2];
        float mx = fmaxf(sv[0], fmaxf(sv[1], sv[2]));
        float e0 = __expf(sv[0] - mx), e1 = __expf(sv[1] - mx), e2 = __expf(sv[2] - mx);
        float inv = natt_s[tid] / (e0 + e1 + e2);
        aw_s[tid][0] = e0 * inv; aw_s[tid][1] = e1 * inv; aw_s[tid][2] = e2 * inv;
    }
    __syncthreads();                                               // B7

    // ---- P7: combine wt = sum_v aw_v*vv_v -> zb0 (lane-owned) ----
    {
        u16* z0p = S + MB * LDA;
        u16* z1p = S + 2 * MB * LDA;
        u16* z2p = S + 3 * MB * LDA;
        for (int idx = tid; idx < MB * 128; idx += 768) {
            int row = idx >> 7, col = idx & 127;
            float w = aw_s[row][0] * b2f(z0p[row * LDA + col]) +
                      aw_s[row][1] * b2f(z1p[row * LDA + col]) +
                      aw_s[row][2] * b2f(z2p[row * LDA + col]);
            z0p[row * LDA + col] = f2b(w);
        }
    }
    __syncthreads();                                               // B8

    // ---- P8: fusion gemms, one per group ----
    f32x4 accG[4][2] = {{zz, zz}, {zz, zz}, {zz, zz}, {zz, zz}};
    if (g == 0) {
        gemm64(xA, W1T, accG);
        #pragma unroll
        for (int mt = 0; mt < 4; ++mt)
            #pragma unroll
            for (int nt = 0; nt < 2; ++nt)
                #pragma unroll
                for (int r = 0; r < 4; ++r)
                    F1[(mt * 16 + q * 4 + r) * 128 + nb + nt * 16 + i] = accG[mt][nt][r];
    } else if (g == 1) {
        gemm64(S + MB * LDA, fus2T, accG);   // wt @ fus_w[128:], kept in regs
    } else {
        gemm64(xA, ftT, accG);               // accT kept in regs
    }
    __syncthreads();                                               // B9
    if (g == 1) {                            // xA+zb0 now dead -> write F2
        #pragma unroll
        for (int mt = 0; mt < 4; ++mt)
            #pragma unroll
            for (int nt = 0; nt < 2; ++nt)
                #pragma unroll
                for (int r = 0; r < 4; ++r)
                    F2[(mt * 16 + q * 4 + r) * 128 + nb + nt * 16 + i] = accG[mt][nt][r];
    }
    __syncthreads();                                               // B9b

    // ---- P9: g2: out = relu(F1+F2+b1) + accT + ftb (in place -> F1); LN red --
    if (g == 2) {
        float b1v0 = b1[nb + i], b1v1 = b1[nb + 16 + i];
        float fb0 = P[P_FTB + nb + i], fb1 = P[P_FTB + nb + 16 + i];
        #pragma unroll
        for (int mt = 0; mt < 4; ++mt) {
            float ps[4] = {0.f, 0.f, 0.f, 0.f}, pq[4] = {0.f, 0.f, 0.f, 0.f};
            #pragma unroll
            for (int nt = 0; nt < 2; ++nt) {
                int col = nb + nt * 16 + i;
                float bv = nt ? b1v1 : b1v0;
                float fv = nt ? fb1 : fb0;
                #pragma unroll
                for (int r = 0; r < 4; ++r) {
                    int rc = (mt * 16 + q * 4 + r) * 128 + col;
                    float o = fmaxf(F1[rc] + F2[rc] + bv, 0.f) + accG[mt][nt][r] + fv;
                    F1[rc] = o;
                    ps[r] += o; pq[r] += o * o;
                }
            }
            #pragma unroll
            for (int s = 1; s <= 8; s <<= 1)
                #pragma unroll
                for (int r = 0; r < 4; ++r) {
                    ps[r] += __shfl_xor(ps[r], s);
                    pq[r] += __shfl_xor(pq[r], s);
                }
            if (i == 0)
                #pragma unroll
                for (int r = 0; r < 4; ++r) {
                    int row = mt * 16 + q * 4 + r;
                    red2[(wid * MB + row) * 2 + 0] = ps[r];
                    red2[(wid * MB + row) * 2 + 1] = pq[r];
                }
        }
    }
    __syncthreads();                                               // B10

    // ---- P10: LN stats (tid<64) ----
    if (tid < MB) {
        float sm = red2[tid * 2]            + red2[(MB + tid) * 2] +
                   red2[(2 * MB + tid) * 2] + red2[(3 * MB + tid) * 2];
        float sq = red2[tid * 2 + 1]            + red2[(MB + tid) * 2 + 1] +
                   red2[(2 * MB + tid) * 2 + 1] + red2[(3 * MB + tid) * 2 + 1];
        float mu = sm * (1.f / 128.f);
        float var = sq * (1.f / 128.f) - mu * mu;
        mrs_s[tid][0] = mu; mrs_s[tid][1] = rsqrtf(var + 1e-5f);
    }
    __syncthreads();                                               // B11

    // ---- P11: normalize from F1 and store directly (all 768 threads) ----
    if (f32) {
        float* op = (float*)d_out + (size_t)nodebase * 128;
        for (int idx = tid; idx < MB * 128; idx += 768) {
            int row = idx >> 7;
            if (nodebase + row < N_) {
                int col = idx & 127;
                float val = (F1[idx] - mrs_s[row][0]) * mrs_s[row][1]
                            * P[P_LNG + col] + P[P_LNB + col];
                op[idx] = val;
            }
        }
    } else {
        unsigned* op = (unsigned*)d_out + (size_t)nodebase * 64;
        for (int idx = tid; idx < MB * 64; idx += 768) {
            int row = idx >> 6;
            if (nodebase + row < N_) {
                int c2 = (idx & 63) * 2;
                float m0 = mrs_s[row][0], r0 = mrs_s[row][1];
                float v0 = (F1[row * 128 + c2]     - m0) * r0 * P[P_LNG + c2]     + P[P_LNB + c2];
                float v1 = (F1[row * 128 + c2 + 1] - m0) * r0 * P[P_LNG + c2 + 1] + P[P_LNB + c2 + 1];
                op[idx] = (unsigned)f2b(v0) | ((unsigned)f2b(v1) << 16);
            }
        }
    }
}

extern "C" void kernel_launch(void* const* d_in, const int* in_sizes, int n_in,
                              void* d_out, int out_size, void* d_ws, size_t ws_size,
                              hipStream_t stream) {
    const void* feat     = d_in[0];
    const int*  ei       = (const int*)d_in[1];
    const void* ew       = d_in[2];
    const void* rel_w    = d_in[3];
    const void* rel_b    = d_in[4];
    const void* gate_w   = d_in[5];
    const void* gate_b   = d_in[6];
    const void* la_w1    = d_in[7];
    const void* la_b1    = d_in[8];
    const void* la_w2    = d_in[9];
    const void* la_b2    = d_in[10];
    const void* pred_w   = d_in[11];
    const void* pred_b   = d_in[12];
    const void* att_bias = d_in[13];
    const void* view_pref= d_in[14];
    const void* va_w1    = d_in[15];
    const void* va_b1    = d_in[16];
    const void* va_w2    = d_in[17];
    const void* va_b2    = d_in[18];
    const void* ft_w     = d_in[19];
    const void* ft_b     = d_in[20];
    const void* sl_w     = d_in[21];
    const void* sl_b     = d_in[22];
    const void* fus_w    = d_in[23];
    const void* fus_b    = d_in[24];
    const void* ln_g     = d_in[25];
    const void* ln_beta  = d_in[26];

    // workspace layout (~38 MB total)
    int*   flag  = (int*)d_ws;                    // 4 ints
    int*   offs3 = flag + 4;                      // 3N
    int*   cur3  = offs3 + 3 * N_;                // 3N
    int2*  srcw3 = (int2*)(cur3 + 3 * N_);        // 3E int2 (16B-aligned)
    int*   bsum  = (int*)(srcw3 + 3 * E_);        // 3*128
    float* b1    = (float*)(bsum + 3 * 128);      // 128
    float* P     = b1 + 128;                      // 2182 (pad to 2304)
    u16*   W1T   = (u16*)(P + 2304);              // 16384
    u16*   relT  = W1T + 16384;                   // 3*16384
    u16*   gateT = relT + 3 * 16384;              // 3*16384
    u16*   vaT   = gateT + 3 * 16384;             // 8192
    u16*   fus2T = vaT + 8192;                    // 16384
    u16*   ftT   = fus2T + 16384;                 // 16384
    u16*   laT   = ftT + 16384;                   // 16384
    u16*   featB = laT + 16384;                   // N*128 bf16 (f32 input case)

    k_detect<<<1, 64, 0, stream>>>((const u16*)feat, flag);
    (void)hipMemsetAsync(cur3, 0, 3 * N_ * sizeof(int), stream);
    k_preC<<<PRE_TOT, 256, 0, stream>>>(flag, feat, featB,
                                        sl_w, sl_b, fus_w, fus_b, W1T, b1,
                                        rel_w, gate_w, va_w1, ft_w, la_w1,
                                        rel_b, gate_b, view_pref,
                                        va_b1, va_w2, va_b2,
                                        la_b1, la_w2, la_b2,
                                        pred_b, att_bias, ft_b, ln_g, ln_beta, pred_w,
                                        relT, gateT, vaT, fus2T, ftT, laT, P,
                                        ei, cur3);
    k_scan_bsum<<<3 * NB_SCAN, 256, 0, stream>>>(cur3, bsum);
    k_scan_write<<<3 * NB_SCAN, 256, 0, stream>>>(cur3, bsum, offs3);
    k_place<<<3 * EGRID, 256, 0, stream>>>(flag, ei, ew, cur3, srcw3);
    k_fused<<<NBLK, 768, 0, stream>>>(flag, feat, featB, srcw3, offs3, cur3,
                                      relT, gateT, vaT, W1T, fus2T, ftT, laT,
                                      b1, P, d_out);
}

// Round 7
// 577.227 us; speedup vs baseline: 1.0578x; 1.0578x over previous
//
#include <hip/hip_runtime.h>

#define N_ 100000
#define D_ 128
#define O_ 128
#define V_ 3
#define E_ 400000
#define NB_SCAN 98   // ceil(N/1024)
#define EGRID 1563   // ceil(E/256)
#define MB 64        // nodes per k_fused block
#define NBLK 1563    // ceil(N/64); last block has 32 valid rows
#define LDA 136      // padded bf16 row stride (16B-aligned)

// fused pre-kernel block ranges
#define PRE_CVT  6250                   // feature cvt (f32 path only)
#define PRE_PREW (PRE_CVT + 64)         // 6314
#define PRE_PREP (PRE_PREW + 681)       // 6995 (prep ids now 174214 -> 681 blocks)
#define PRE_TOT  (PRE_PREP + 3 * EGRID) // 11684

typedef unsigned short u16;
typedef __attribute__((ext_vector_type(8))) short bf16x8;   // 8 bf16 = 4 VGPRs
typedef __attribute__((ext_vector_type(4))) float f32x4;

#define MFMA16x16x32 __builtin_amdgcn_mfma_f32_16x16x32_bf16

// ---- fp32 param block offsets (in workspace, filled by prep) ----
#define P_RELB  0
#define P_GATEB 384
#define P_VP    768
#define P_VAB1  1152
#define P_VAW2  1216
#define P_VAB2  1280
#define P_LAB1  1281
#define P_LAW2  1409
#define P_LAB2  1537
#define P_PREDB 1539
#define P_ATTB  1541
#define P_FTB   1542
#define P_LNG   1670
#define P_LNB   1798
#define P_PREDW 1926
#define P_TOTAL 2182

__device__ __forceinline__ float b2f(u16 u) {
    union { float f; unsigned int i; } x; x.i = ((unsigned int)u) << 16; return x.f;
}
__device__ __forceinline__ float blo(unsigned int u) {
    union { float f; unsigned int i; } x; x.i = u << 16; return x.f;
}
__device__ __forceinline__ float bhi(unsigned int u) {
    union { float f; unsigned int i; } x; x.i = u & 0xffff0000u; return x.f;
}
__device__ __forceinline__ u16 f2b(float f) {
    union { float f; unsigned int i; } x; x.f = f;
    unsigned int r = x.i + 0x7FFFu + ((x.i >> 16) & 1u);
    return (u16)(r >> 16);
}

template<int F32> __device__ __forceinline__ float LD(const void* p, size_t i) {
    if (F32) return ((const float*)p)[i];
    return b2f(((const u16*)p)[i]);
}

// ---------------- dtype detector: fp32 vs bf16 element stream ----------------
__global__ void k_detect(const u16* __restrict__ feat, int* __restrict__ flag) {
    int t = threadIdx.x;   // 64 lanes; check feat[2i], i = t and t+64
    u16 a = feat[2 * t], b = feat[2 * t + 128];
    int zeros = (a == 0 ? 1 : 0) + (b == 0 ? 1 : 0);
    float va = b2f(a), vb = b2f(b);
    int bad = (!(va > -128.f && va < 128.f) ? 1 : 0) +
              (!(vb > -128.f && vb < 128.f) ? 1 : 0);
    #pragma unroll
    for (int s = 1; s <= 32; s <<= 1) {
        bad += __shfl_xor(bad, s);
        zeros += __shfl_xor(zeros, s);
    }
    if (t == 0) flag[0] = (bad >= 16 || zeros >= 64) ? 1 : 0;
}

// ---------------- fused pre kernel: cvt | prew | prep | count ----------------
__device__ __forceinline__ void cvt_body_f32(int b, const void* feat,
                                             u16* __restrict__ featB) {
    size_t idx = (size_t)b * 256 + threadIdx.x;   // 8 elems per thread
    const float4* fp = (const float4*)feat;
    float4 a = fp[idx * 2], c = fp[idx * 2 + 1];
    uint4 u;
    u.x = (unsigned)f2b(a.x) | ((unsigned)f2b(a.y) << 16);
    u.y = (unsigned)f2b(a.z) | ((unsigned)f2b(a.w) << 16);
    u.z = (unsigned)f2b(c.x) | ((unsigned)f2b(c.y) << 16);
    u.w = (unsigned)f2b(c.z) | ((unsigned)f2b(c.w) << 16);
    ((uint4*)featB)[idx] = u;
}

template<int F32>
__device__ __forceinline__ void prew_body(int b, const void* sl_w, const void* sl_b,
                                          const void* fus_w, const void* fus_b,
                                          u16* __restrict__ W1T, float* __restrict__ b1) {
    int gid = b * 256 + threadIdx.x;   // 64 blocks
    int d = gid >> 7, o = gid & 127;
    float acc = 0.f;
    for (int k = 0; k < 128; ++k)
        acc += LD<F32>(sl_w, d * 128 + k) * LD<F32>(fus_w, k * 128 + o);
    W1T[o * 128 + d] = f2b(acc);
    if (gid < 128) {
        float accb = 0.f;
        for (int k = 0; k < 128; ++k)
            accb += LD<F32>(sl_b, k) * LD<F32>(fus_w, k * 128 + gid);
        b1[gid] = accb + LD<F32>(fus_b, gid);
    }
}

template<int F32>
__device__ __forceinline__ void prep_body(int b,
        const void* rel_w, const void* gate_w, const void* va_w1, const void* fus_w,
        const void* ft_w, const void* la_w1,
        const void* rel_b, const void* gate_b, const void* vpref,
        const void* va_b1, const void* va_w2, const void* va_b2,
        const void* la_b1, const void* la_w2, const void* la_b2,
        const void* pred_b, const void* att_bias, const void* ft_b,
        const void* ln_g, const void* ln_beta, const void* pred_w,
        u16* __restrict__ relT, u16* __restrict__ gateT, u16* __restrict__ vaT3,
        u16* __restrict__ fus2T, u16* __restrict__ ftT, u16* __restrict__ laT,
        float* __restrict__ P) {
    int id = b * 256 + threadIdx.x;
    if (id < 49152) {
        int v = id >> 14, r = id & 16383, o = r >> 7, d = r & 127;
        relT[id] = f2b(LD<F32>(rel_w, (size_t)v * 16384 + d * 128 + o));
    } else if (id < 98304) {
        int t = id - 49152, v = t >> 14, r = t & 16383, o = r >> 7, d = r & 127;
        gateT[t] = f2b(LD<F32>(gate_w, (size_t)v * 16384 + d * 128 + o));
    } else if (id < 122880) {
        // vaT3[v][n][k] = va_w1[k][n] * view_pref[v][k]  (vp folded in)
        int t = id - 98304, v = t >> 13, r = t & 8191, n = r >> 7, k = r & 127;
        vaT3[t] = f2b(LD<F32>(va_w1, k * 64 + n) * LD<F32>(vpref, v * 128 + k));
    } else if (id < 139264) {
        int t = id - 122880, n = t >> 7, k = t & 127;
        fus2T[t] = f2b(LD<F32>(fus_w, (128 + k) * 128 + n));
    } else if (id < 155648) {
        int t = id - 139264, o = t >> 7, d = t & 127;
        ftT[t] = f2b(LD<F32>(ft_w, d * 128 + o));
    } else if (id < 172032) {
        int t = id - 155648, n = t >> 7, d = t & 127;
        int c = n >> 6, j = n & 63;
        laT[t] = f2b(LD<F32>(la_w1, c * 8192 + d * 64 + j));
    } else if (id < 172032 + P_TOTAL) {
        int t = id - 172032;
        float val;
        if      (t < P_GATEB) val = LD<F32>(rel_b, t);
        else if (t < P_VP)    val = LD<F32>(gate_b, t - P_GATEB);
        else if (t < P_VAB1)  val = LD<F32>(vpref, t - P_VP);
        else if (t < P_VAW2)  val = LD<F32>(va_b1, t - P_VAB1);
        else if (t < P_VAB2)  val = LD<F32>(va_w2, t - P_VAW2);
        else if (t < P_LAB1)  val = LD<F32>(va_b2, 0);
        else if (t < P_LAW2)  val = LD<F32>(la_b1, t - P_LAB1);
        else if (t < P_LAB2)  val = LD<F32>(la_w2, t - P_LAW2);
        else if (t < P_PREDB) val = LD<F32>(la_b2, t - P_LAB2);
        else if (t < P_ATTB)  val = LD<F32>(pred_b, t - P_PREDB);
        else if (t < P_FTB)   val = LD<F32>(att_bias, 0);
        else if (t < P_LNG)   val = LD<F32>(ft_b, t - P_FTB);
        else if (t < P_LNB)   val = LD<F32>(ln_g, t - P_LNG);
        else if (t < P_PREDW) val = LD<F32>(ln_beta, t - P_LNB);
        else                  val = LD<F32>(pred_w, t - P_PREDW);
        P[t] = val;
    }
}

__global__ __launch_bounds__(256) void k_preC(const int* __restrict__ flag,
        const void* feat, u16* __restrict__ featB,
        const void* sl_w, const void* sl_b, const void* fus_w, const void* fus_b,
        u16* __restrict__ W1T, float* __restrict__ b1,
        const void* rel_w, const void* gate_w, const void* va_w1,
        const void* ft_w, const void* la_w1,
        const void* rel_b, const void* gate_b, const void* vpref,
        const void* va_b1, const void* va_w2, const void* va_b2,
        const void* la_b1, const void* la_w2, const void* la_b2,
        const void* pred_b, const void* att_bias, const void* ft_b,
        const void* ln_g, const void* ln_beta, const void* pred_w,
        u16* __restrict__ relT, u16* __restrict__ gateT, u16* __restrict__ vaT3,
        u16* __restrict__ fus2T, u16* __restrict__ ftT, u16* __restrict__ laT,
        float* __restrict__ P,
        const int* __restrict__ ei, int* __restrict__ cur3) {
    int b = blockIdx.x;
    if (b < PRE_CVT) {
        if (flag[0]) cvt_body_f32(b, feat, featB);   // bf16 case: featB unused
    } else if (b < PRE_PREW) {
        if (flag[0]) prew_body<1>(b - PRE_CVT, sl_w, sl_b, fus_w, fus_b, W1T, b1);
        else         prew_body<0>(b - PRE_CVT, sl_w, sl_b, fus_w, fus_b, W1T, b1);
    } else if (b < PRE_PREP) {
        if (flag[0]) prep_body<1>(b - PRE_PREW, rel_w, gate_w, va_w1, fus_w, ft_w, la_w1,
                                  rel_b, gate_b, vpref, va_b1, va_w2, va_b2,
                                  la_b1, la_w2, la_b2, pred_b, att_bias, ft_b,
                                  ln_g, ln_beta, pred_w, relT, gateT, vaT3, fus2T, ftT, laT, P);
        else         prep_body<0>(b - PRE_PREW, rel_w, gate_w, va_w1, fus_w, ft_w, la_w1,
                                  rel_b, gate_b, vpref, va_b1, va_w2, va_b2,
                                  la_b1, la_w2, la_b2, pred_b, att_bias, ft_b,
                                  ln_g, ln_beta, pred_w, relT, gateT, vaT3, fus2T, ftT, laT, P);
    } else {
        int b2 = b - PRE_PREP;
        int v = b2 / EGRID;
        int e = (b2 % EGRID) * 256 + threadIdx.x;
        if (e < E_) atomicAdd(&cur3[v * N_ + ei[(size_t)v * 2 * E_ + E_ + e]], 1);
    }
}

// ---------------- CSR scan: bsum / write (inline spine) ----------------------
__global__ __launch_bounds__(256) void k_scan_bsum(const int* __restrict__ cur3,
                                                   int* __restrict__ bsum) {
    __shared__ int red[256];
    const int v = blockIdx.x / NB_SCAN, b = blockIdx.x % NB_SCAN, tid = threadIdx.x;
    const int base = b * 1024;
    const int* counts = cur3 + v * N_;
    int s = 0;
    for (int i = tid; i < 1024; i += 256) {
        int idx = base + i;
        s += (idx < N_) ? counts[idx] : 0;
    }
    red[tid] = s;
    __syncthreads();
    for (int st = 128; st >= 1; st >>= 1) {
        if (tid < st) red[tid] += red[tid + st];
        __syncthreads();
    }
    if (tid == 0) bsum[v * 128 + b] = red[0];
}

__global__ __launch_bounds__(256) void k_scan_write(int* __restrict__ cur3,
                                                    const int* __restrict__ bsum,
                                                    int* __restrict__ offs3) {
    __shared__ int lsum[256];
    __shared__ int bs_s[128];
    const int v = blockIdx.x / NB_SCAN, b = blockIdx.x % NB_SCAN, tid = threadIdx.x;
    const int base = b * 1024;
    int* counts = cur3 + v * N_;
    int* offs   = offs3 + v * N_;
    if (tid < 128) bs_s[tid] = (tid < b) ? bsum[v * 128 + tid] : 0;
    int c[4]; int s = 0;
    #pragma unroll
    for (int k = 0; k < 4; ++k) {
        int idx = base + tid * 4 + k;
        c[k] = (idx < N_) ? counts[idx] : 0;
        s += c[k];
    }
    lsum[tid] = s;
    __syncthreads();
    for (int st = 1; st < 256; st <<= 1) {
        int t = (tid >= st) ? lsum[tid - st] : 0;
        __syncthreads();
        lsum[tid] += t;
        __syncthreads();
    }
    for (int st = 64; st >= 1; st >>= 1) {
        if (tid < st) bs_s[tid] += bs_s[tid + st];
        __syncthreads();
    }
    int off = bs_s[0] + lsum[tid] - s;
    #pragma unroll
    for (int k = 0; k < 4; ++k) {
        int idx = base + tid * 4 + k;
        if (idx < N_) { offs[idx] = off; counts[idx] = off; }
        off += c[k];
    }
}

// place: srcw[pos] = {src, weight-bits}
template<int F32>
__device__ __forceinline__ void place_body(const int* __restrict__ ei, const void* ew_all,
                                           int* __restrict__ cur3, int2* __restrict__ srcw3) {
    int v = blockIdx.x / EGRID;
    int e = (blockIdx.x % EGRID) * 256 + threadIdx.x;
    if (e < E_) {
        int dst = ei[(size_t)v * 2 * E_ + E_ + e];
        int src = ei[(size_t)v * 2 * E_ + e];
        float w = LD<F32>(ew_all, (size_t)v * E_ + e);
        int pos = atomicAdd(&cur3[v * N_ + dst], 1);
        int2 sw; sw.x = src; sw.y = __float_as_int(w);
        srcw3[(size_t)v * E_ + pos] = sw;
    }
    // afterwards cur3[v*N+n] == row end
}
__global__ __launch_bounds__(256) void k_place(const int* __restrict__ flag,
                                               const int* __restrict__ ei, const void* ew,
                                               int* __restrict__ cur3, int2* __restrict__ srcw3) {
    if (flag[0]) place_body<1>(ei, ew, cur3, srcw3);
    else         place_body<0>(ei, ew, cur3, srcw3);
}

// ------ fused MFMA pipeline: MB=64, 768 threads, view-parallel groups --------
// Register discipline (r6 spill post-mortem): only ONE 32-reg accumulator
// live per phase. agg is re-read from zc (bf16) in P4 instead of carrying
// accA across the gate GEMM; view_pref is folded into vaT3 at prep.
__global__ __launch_bounds__(768, 6) void k_fused(const int* __restrict__ flag,
        const void* feat, const u16* __restrict__ featB_,
        const int2* __restrict__ srcw3,
        const int* __restrict__ offs3, const int* __restrict__ ends3,
        const u16* __restrict__ relT, const u16* __restrict__ gateT,
        const u16* __restrict__ vaT3, const u16* __restrict__ W1T,
        const u16* __restrict__ fus2T, const u16* __restrict__ ftT,
        const u16* __restrict__ laT,
        const float* __restrict__ b1, const float* __restrict__ P,
        void* __restrict__ d_out) {
    const int f32 = flag[0];
    const u16* __restrict__ fb = f32 ? featB_ : (const u16*)feat;

    __shared__ __align__(16) u16 S[4 * MB * LDA];     // xA | zb0 | zb1 | zb2
    __shared__ float redL[4][MB];
    __shared__ float redv[3][4][MB];                  // va reduce; overlay LN red2
    __shared__ float wsn3[3][MB];
    __shared__ float aw_s[MB][3];
    __shared__ float natt_s[MB];
    __shared__ float lg_s[MB][2];
    __shared__ float mrs_s[MB][2];

    u16* xA = S;
    float* F1 = (float*)(S + 2 * MB * LDA);   // 32KB over zb1+zb2
    float* F2 = (float*)S;                    // 32KB over xA+zb0
    float* red2 = &redv[0][0][0];             // [4][MB][2] overlay (512 f32)

    const int tid = threadIdx.x;
    const int g   = tid >> 8;               // wave-group / view 0..2
    const int t256 = tid & 255;
    const int wid = t256 >> 6;              // wave within group 0..3
    const int L = t256 & 63, q = L >> 4, i = L & 15;
    const int nb = wid * 32;
    const int nodebase = blockIdx.x * MB;
    const int nl = t256 >> 5, l32 = t256 & 31, o4 = l32 * 4;
    const int gsub = t256 >> 4, l16 = tid & 15, o8 = l16 * 8;
    const f32x4 zz = {0.f, 0.f, 0.f, 0.f};
    u16* zc = S + (size_t)(1 + g) * MB * LDA;   // this group's z buffer

    auto ldf = [&](const u16* B, int row, int k0) -> bf16x8 {
        return *(const bf16x8*)&B[row * LDA + k0];
    };
    auto ldg = [&](const u16* B, int row, int k0) -> bf16x8 {
        return *(const bf16x8*)&B[row * 128 + k0];
    };
    // M=64 gemm by the 4 waves of one group: acc[mt][nt], rows mt*16+q*4+r
    auto gemm64 = [&](const u16* A, const u16* Bg, f32x4 acc[4][2]) {
        #pragma unroll
        for (int kk = 0; kk < 4; ++kk) {
            int k0 = q * 8 + kk * 32;
            bf16x8 bb0 = ldg(Bg, nb + i, k0);
            bf16x8 bb1 = ldg(Bg, nb + 16 + i, k0);
            #pragma unroll
            for (int mt = 0; mt < 4; ++mt) {
                bf16x8 a = ldf(A, i + mt * 16, k0);
                acc[mt][0] = MFMA16x16x32(a, bb0, acc[mt][0], 0, 0, 0);
                acc[mt][1] = MFMA16x16x32(a, bb1, acc[mt][1], 0, 0, 0);
            }
        }
    };
    // gather view g: 16 subgroups of 16 lanes; 4 nodes per subgroup
    auto gather = [&]() {
        const int* offs = offs3 + g * N_;
        const int* ends = ends3 + g * N_;
        const int2* srcw = srcw3 + (size_t)g * E_;
        #pragma unroll
        for (int rep = 0; rep < 4; ++rep) {
            const int m = gsub + rep * 16;
            const int node = nodebase + m;
            if (node < N_) {
                float z0 = 0.f, z1 = 0.f, z2 = 0.f, z3 = 0.f;
                float z4 = 0.f, z5 = 0.f, z6 = 0.f, z7 = 0.f, ws = 0.f;
                int j = offs[node], jend = ends[node];
                while (j < jend) {
                    int r = jend - j;
                    int2 e0 = srcw[j];
                    int2 e1, e2, e3;
                    e1.x = 0; e1.y = 0; e2.x = 0; e2.y = 0; e3.x = 0; e3.y = 0;
                    if (r > 1) e1 = srcw[j + 1];
                    if (r > 2) e2 = srcw[j + 2];
                    if (r > 3) e3 = srcw[j + 3];
                    uint4 x0, x1, x2, x3;
                    x1.x = x1.y = x1.z = x1.w = 0;
                    x2.x = x2.y = x2.z = x2.w = 0;
                    x3.x = x3.y = x3.z = x3.w = 0;
                    x0 = *(const uint4*)&fb[(size_t)e0.x * 128 + o8];
                    if (r > 1) x1 = *(const uint4*)&fb[(size_t)e1.x * 128 + o8];
                    if (r > 2) x2 = *(const uint4*)&fb[(size_t)e2.x * 128 + o8];
                    if (r > 3) x3 = *(const uint4*)&fb[(size_t)e3.x * 128 + o8];
                    float w0 = __int_as_float(e0.y), w1 = __int_as_float(e1.y);
                    float w2 = __int_as_float(e2.y), w3 = __int_as_float(e3.y);
                    ws += w0 + w1 + w2 + w3;
                    z0 += w0 * blo(x0.x) + w1 * blo(x1.x) + w2 * blo(x2.x) + w3 * blo(x3.x);
                    z1 += w0 * bhi(x0.x) + w1 * bhi(x1.x) + w2 * bhi(x2.x) + w3 * bhi(x3.x);
                    z2 += w0 * blo(x0.y) + w1 * blo(x1.y) + w2 * blo(x2.y) + w3 * blo(x3.y);
                    z3 += w0 * bhi(x0.y) + w1 * bhi(x1.y) + w2 * bhi(x2.y) + w3 * bhi(x3.y);
                    z4 += w0 * blo(x0.z) + w1 * blo(x1.z) + w2 * blo(x2.z) + w3 * blo(x3.z);
                    z5 += w0 * bhi(x0.z) + w1 * bhi(x1.z) + w2 * bhi(x2.z) + w3 * bhi(x3.z);
                    z6 += w0 * blo(x0.w) + w1 * blo(x1.w) + w2 * blo(x2.w) + w3 * blo(x3.w);
                    z7 += w0 * bhi(x0.w) + w1 * bhi(x1.w) + w2 * bhi(x2.w) + w3 * bhi(x3.w);
                    j += 4;
                }
                uint4 u;
                u.x = (unsigned)f2b(z0) | ((unsigned)f2b(z1) << 16);
                u.y = (unsigned)f2b(z2) | ((unsigned)f2b(z3) << 16);
                u.z = (unsigned)f2b(z4) | ((unsigned)f2b(z5) << 16);
                u.w = (unsigned)f2b(z6) | ((unsigned)f2b(z7) << 16);
                *(uint4*)&zc[m * LDA + o8] = u;
                if (l16 == 0) wsn3[g][m] = ws;
            }
        }
    };

    // ---- P0: stage xA (zero-pad tail rows); each group gathers ----
    for (int idx = tid; idx < MB * 16; idx += 768) {
        int m = idx >> 4, s = idx & 15;
        int node = nodebase + m;
        uint4 u; u.x = 0; u.y = 0; u.z = 0; u.w = 0;
        if (node < N_) u = *(const uint4*)&fb[(size_t)node * 128 + s * 8];
        *(uint4*)&xA[m * LDA + s * 8] = u;
    }
    gather();
    __syncthreads();                                               // B1

    // ---- P1: g0 label-attention FIRST (accL freed), then all rel gemms ----
    if (g == 0) {
        f32x4 accL[4][2] = {{zz, zz}, {zz, zz}, {zz, zz}, {zz, zz}};
        gemm64(xA, laT, accL);
        float pw[8];
        #pragma unroll
        for (int t = 0; t < 4; ++t) {
            pw[2 * t]     = P[P_PREDW + (o4 + t) * 2];
            pw[2 * t + 1] = P[P_PREDW + (o4 + t) * 2 + 1];
        }
        #pragma unroll
        for (int rep = 0; rep < 8; ++rep) {
            int m = rep * 8 + nl;
            float lg0 = 0.f, lg1 = 0.f;
            #pragma unroll
            for (int t = 0; t < 4; ++t) {
                float xv = b2f(xA[m * LDA + o4 + t]);
                lg0 += xv * pw[2 * t];
                lg1 += xv * pw[2 * t + 1];
            }
            #pragma unroll
            for (int s = 1; s <= 16; s <<= 1) {
                lg0 += __shfl_xor(lg0, s);
                lg1 += __shfl_xor(lg1, s);
            }
            if (l32 == 0) { lg_s[m][0] = lg0; lg_s[m][1] = lg1; }
        }
        float la0 = P[P_LAB1 + nb + i],  la1 = P[P_LAB1 + nb + 16 + i];
        float lw0 = P[P_LAW2 + nb + i],  lw1 = P[P_LAW2 + nb + 16 + i];
        #pragma unroll
        for (int mt = 0; mt < 4; ++mt) {
            float partL[4];
            #pragma unroll
            for (int r = 0; r < 4; ++r) {
                float h0 = fmaxf(accL[mt][0][r] + la0, 0.f);
                float h1 = fmaxf(accL[mt][1][r] + la1, 0.f);
                partL[r] = h0 * lw0 + h1 * lw1;
            }
            #pragma unroll
            for (int s = 1; s <= 8; s <<= 1)
                #pragma unroll
                for (int r = 0; r < 4; ++r)
                    partL[r] += __shfl_xor(partL[r], s);
            if (i == 0)
                #pragma unroll
                for (int r = 0; r < 4; ++r)
                    redL[wid][mt * 16 + q * 4 + r] = partL[r];
        }
    }
    {
        f32x4 accA[4][2] = {{zz, zz}, {zz, zz}, {zz, zz}, {zz, zz}};
        gemm64(zc, relT + (size_t)g * 16384, accA);
        __syncthreads();                                           // B2
        // ---- P2: agg = acc + wsn*rel_b -> zc (accA dies here) ----
        float rb0 = P[P_RELB + g * 128 + nb + i];
        float rb1 = P[P_RELB + g * 128 + nb + 16 + i];
        #pragma unroll
        for (int mt = 0; mt < 4; ++mt)
            #pragma unroll
            for (int nt = 0; nt < 2; ++nt) {
                float rb = nt ? rb1 : rb0;
                int col = nb + nt * 16 + i;
                #pragma unroll
                for (int r = 0; r < 4; ++r) {
                    int row = mt * 16 + q * 4 + r;
                    zc[row * LDA + col] = f2b(accA[mt][nt][r] + wsn3[g][row] * rb);
                }
            }
    }
    if (tid < MB) {
        float c0 = redL[0][tid] + redL[1][tid] + P[P_LAB2 + 0];
        float c1 = redL[2][tid] + redL[3][tid] + P[P_LAB2 + 1];
        float s0 = 1.f / (1.f + __expf(-c0));
        float s1 = 1.f / (1.f + __expf(-c1));
        float l0 = lg_s[tid][0] + P[P_PREDB + 0];
        float l1 = lg_s[tid][1] + P[P_PREDB + 1];
        float mx = fmaxf(l0, l1);
        float e0 = __expf(l0 - mx), e1 = __expf(l1 - mx);
        float inv = 1.f / (e0 + e1);
        float p0 = e0 * inv, p1 = e1 * inv;
        natt_s[tid] = s0 * p0 + s1 * p1 + P[P_ATTB];
        int node = nodebase + tid;
        if (node < N_) {
            if (f32) {
                float* pr = (float*)d_out + (size_t)N_ * O_;
                pr[node * 2 + 0] = p0; pr[node * 2 + 1] = p1;
            } else {
                u16* pr = (u16*)d_out + (size_t)N_ * O_;
                pr[node * 2 + 0] = f2b(p0); pr[node * 2 + 1] = f2b(p1);
            }
        }
    }
    __syncthreads();                                               // B3

    // ---- P3: gate gemm; P4: vv = sigmoid(acc2+gb)*agg(zc, bf16) -> zc ----
    {
        f32x4 acc2[4][2] = {{zz, zz}, {zz, zz}, {zz, zz}, {zz, zz}};
        gemm64(zc, gateT + (size_t)g * 16384, acc2);
        __syncthreads();                                           // B4
        float gb0 = P[P_GATEB + g * 128 + nb + i];
        float gb1 = P[P_GATEB + g * 128 + nb + 16 + i];
        #pragma unroll
        for (int mt = 0; mt < 4; ++mt)
            #pragma unroll
            for (int nt = 0; nt < 2; ++nt) {
                float gb = nt ? gb1 : gb0;
                int col = nb + nt * 16 + i;
                #pragma unroll
                for (int r = 0; r < 4; ++r) {
                    int row = mt * 16 + q * 4 + r;
                    float agg = b2f(zc[row * LDA + col]);
                    float gt = 1.f / (1.f + __expf(-(acc2[mt][nt][r] + gb)));
                    zc[row * LDA + col] = f2b(gt * agg);
                }
            }
    }
    __syncthreads();                                               // B5

    // ---- P5: va gemm on vv with vp-folded weights (plain MFMA) ----
    {
        f32x4 accV[4] = {zz, zz, zz, zz};
        const int nbv = wid * 16, colv = nbv + i;
        const u16* vaW = vaT3 + (size_t)g * 8192;
        #pragma unroll
        for (int kk = 0; kk < 4; ++kk) {
            int k0 = q * 8 + kk * 32;
            bf16x8 bb = ldg(vaW, nbv + i, k0);
            #pragma unroll
            for (int mt = 0; mt < 4; ++mt) {
                bf16x8 a = ldf(zc, i + mt * 16, k0);
                accV[mt] = MFMA16x16x32(a, bb, accV[mt], 0, 0, 0);
            }
        }
        float vb1v = P[P_VAB1 + colv], vw2v = P[P_VAW2 + colv];
        #pragma unroll
        for (int mt = 0; mt < 4; ++mt) {
            float part[4];
            #pragma unroll
            for (int r = 0; r < 4; ++r) {
                float vh = fmaxf(accV[mt][r] + vb1v, 0.f);
                part[r] = vh * vw2v;
            }
            #pragma unroll
            for (int s = 1; s <= 8; s <<= 1)
                #pragma unroll
                for (int r = 0; r < 4; ++r)
                    part[r] += __shfl_xor(part[r], s);
            if (i == 0)
                #pragma unroll
                for (int r = 0; r < 4; ++r)
                    redv[g][wid][mt * 16 + q * 4 + r] = part[r];
        }
    }
    __syncthreads();                                               // B6

    // ---- P6: vscore + view softmax * natt (tid<64) ----
    if (tid < MB) {
        float sv[3];
        #pragma unroll
        for (int v = 0; v < 3; ++v)
            sv[v] = redv[v][0][tid] + redv[v][1][tid] +
                    redv[v][2][tid] + redv[v][3][tid] + P[P_VAB2];
        float mx = fmaxf(sv[0], fmaxf(sv[1], sv[2]));
        float e0 = __expf(sv[0] - mx), e1 = __expf(sv[1] - mx), e2 = __expf(sv[2] - mx);
        float inv = natt_s[tid] / (e0 + e1 + e2);
        aw_s[tid][0] = e0 * inv; aw_s[tid][1] = e1 * inv; aw_s[tid][2] = e2 * inv;
    }
    __syncthreads();                                               // B7

    // ---- P7: combine wt = sum_v aw_v*vv_v -> zb0 (lane-owned) ----
    {
        u16* z0p = S + MB * LDA;
        u16* z1p = S + 2 * MB * LDA;
        u16* z2p = S + 3 * MB * LDA;
        for (int idx = tid; idx < MB * 128; idx += 768) {
            int row = idx >> 7, col = idx & 127;
            float w = aw_s[row][0] * b2f(z0p[row * LDA + col]) +
                      aw_s[row][1] * b2f(z1p[row * LDA + col]) +
                      aw_s[row][2] * b2f(z2p[row * LDA + col]);
            z0p[row * LDA + col] = f2b(w);
        }
    }
    __syncthreads();                                               // B8

    // ---- P8: fusion gemms, one per group ----
    f32x4 accG[4][2] = {{zz, zz}, {zz, zz}, {zz, zz}, {zz, zz}};
    if (g == 0) {
        gemm64(xA, W1T, accG);
        #pragma unroll
        for (int mt = 0; mt < 4; ++mt)
            #pragma unroll
            for (int nt = 0; nt < 2; ++nt)
                #pragma unroll
                for (int r = 0; r < 4; ++r)
                    F1[(mt * 16 + q * 4 + r) * 128 + nb + nt * 16 + i] = accG[mt][nt][r];
    } else if (g == 1) {
        gemm64(S + MB * LDA, fus2T, accG);   // wt @ fus_w[128:], kept in regs
    } else {
        gemm64(xA, ftT, accG);               // accT kept in regs
    }
    __syncthreads();                                               // B9
    if (g == 1) {                            // xA+zb0 now dead -> write F2
        #pragma unroll
        for (int mt = 0; mt < 4; ++mt)
            #pragma unroll
            for (int nt = 0; nt < 2; ++nt)
                #pragma unroll
                for (int r = 0; r < 4; ++r)
                    F2[(mt * 16 + q * 4 + r) * 128 + nb + nt * 16 + i] = accG[mt][nt][r];
    }
    __syncthreads();                                               // B9b

    // ---- P9: g2: out = relu(F1+F2+b1) + accT + ftb (in place -> F1); LN red --
    if (g == 2) {
        float b1v0 = b1[nb + i], b1v1 = b1[nb + 16 + i];
        float fb0 = P[P_FTB + nb + i], fb1 = P[P_FTB + nb + 16 + i];
        #pragma unroll
        for (int mt = 0; mt < 4; ++mt) {
            float ps[4] = {0.f, 0.f, 0.f, 0.f}, pq[4] = {0.f, 0.f, 0.f, 0.f};
            #pragma unroll
            for (int nt = 0; nt < 2; ++nt) {
                int col = nb + nt * 16 + i;
                float bv = nt ? b1v1 : b1v0;
                float fv = nt ? fb1 : fb0;
                #pragma unroll
                for (int r = 0; r < 4; ++r) {
                    int rc = (mt * 16 + q * 4 + r) * 128 + col;
                    float o = fmaxf(F1[rc] + F2[rc] + bv, 0.f) + accG[mt][nt][r] + fv;
                    F1[rc] = o;
                    ps[r] += o; pq[r] += o * o;
                }
            }
            #pragma unroll
            for (int s = 1; s <= 8; s <<= 1)
                #pragma unroll
                for (int r = 0; r < 4; ++r) {
                    ps[r] += __shfl_xor(ps[r], s);
                    pq[r] += __shfl_xor(pq[r], s);
                }
            if (i == 0)
                #pragma unroll
                for (int r = 0; r < 4; ++r) {
                    int row = mt * 16 + q * 4 + r;
                    red2[(wid * MB + row) * 2 + 0] = ps[r];
                    red2[(wid * MB + row) * 2 + 1] = pq[r];
                }
        }
    }
    __syncthreads();                                               // B10

    // ---- P10: LN stats (tid<64) ----
    if (tid < MB) {
        float sm = red2[tid * 2]            + red2[(MB + tid) * 2] +
                   red2[(2 * MB + tid) * 2] + red2[(3 * MB + tid) * 2];
        float sq = red2[tid * 2 + 1]            + red2[(MB + tid) * 2 + 1] +
                   red2[(2 * MB + tid) * 2 + 1] + red2[(3 * MB + tid) * 2 + 1];
        float mu = sm * (1.f / 128.f);
        float var = sq * (1.f / 128.f) - mu * mu;
        mrs_s[tid][0] = mu; mrs_s[tid][1] = rsqrtf(var + 1e-5f);
    }
    __syncthreads();                                               // B11

    // ---- P11: normalize from F1 and store directly (all 768 threads) ----
    if (f32) {
        float* op = (float*)d_out + (size_t)nodebase * 128;
        for (int idx = tid; idx < MB * 128; idx += 768) {
            int row = idx >> 7;
            if (nodebase + row < N_) {
                int col = idx & 127;
                float val = (F1[idx] - mrs_s[row][0]) * mrs_s[row][1]
                            * P[P_LNG + col] + P[P_LNB + col];
                op[idx] = val;
            }
        }
    } else {
        unsigned* op = (unsigned*)d_out + (size_t)nodebase * 64;
        for (int idx = tid; idx < MB * 64; idx += 768) {
            int row = idx >> 6;
            if (nodebase + row < N_) {
                int c2 = (idx & 63) * 2;
                float m0 = mrs_s[row][0], r0 = mrs_s[row][1];
                float v0 = (F1[row * 128 + c2]     - m0) * r0 * P[P_LNG + c2]     + P[P_LNB + c2];
                float v1 = (F1[row * 128 + c2 + 1] - m0) * r0 * P[P_LNG + c2 + 1] + P[P_LNB + c2 + 1];
                op[idx] = (unsigned)f2b(v0) | ((unsigned)f2b(v1) << 16);
            }
        }
    }
}

extern "C" void kernel_launch(void* const* d_in, const int* in_sizes, int n_in,
                              void* d_out, int out_size, void* d_ws, size_t ws_size,
                              hipStream_t stream) {
    const void* feat     = d_in[0];
    const int*  ei       = (const int*)d_in[1];
    const void* ew       = d_in[2];
    const void* rel_w    = d_in[3];
    const void* rel_b    = d_in[4];
    const void* gate_w   = d_in[5];
    const void* gate_b   = d_in[6];
    const void* la_w1    = d_in[7];
    const void* la_b1    = d_in[8];
    const void* la_w2    = d_in[9];
    const void* la_b2    = d_in[10];
    const void* pred_w   = d_in[11];
    const void* pred_b   = d_in[12];
    const void* att_bias = d_in[13];
    const void* view_pref= d_in[14];
    const void* va_w1    = d_in[15];
    const void* va_b1    = d_in[16];
    const void* va_w2    = d_in[17];
    const void* va_b2    = d_in[18];
    const void* ft_w     = d_in[19];
    const void* ft_b     = d_in[20];
    const void* sl_w     = d_in[21];
    const void* sl_b     = d_in[22];
    const void* fus_w    = d_in[23];
    const void* fus_b    = d_in[24];
    const void* ln_g     = d_in[25];
    const void* ln_beta  = d_in[26];

    // workspace layout (~38 MB total)
    int*   flag  = (int*)d_ws;                    // 4 ints
    int*   offs3 = flag + 4;                      // 3N
    int*   cur3  = offs3 + 3 * N_;                // 3N
    int2*  srcw3 = (int2*)(cur3 + 3 * N_);        // 3E int2 (16B-aligned)
    int*   bsum  = (int*)(srcw3 + 3 * E_);        // 3*128
    float* b1    = (float*)(bsum + 3 * 128);      // 128
    float* P     = b1 + 128;                      // 2182 (pad to 2304)
    u16*   W1T   = (u16*)(P + 2304);              // 16384
    u16*   relT  = W1T + 16384;                   // 3*16384
    u16*   gateT = relT + 3 * 16384;              // 3*16384
    u16*   vaT3  = gateT + 3 * 16384;             // 3*8192 (vp folded)
    u16*   fus2T = vaT3 + 3 * 8192;               // 16384
    u16*   ftT   = fus2T + 16384;                 // 16384
    u16*   laT   = ftT + 16384;                   // 16384
    u16*   featB = laT + 16384;                   // N*128 bf16 (f32 input case)

    k_detect<<<1, 64, 0, stream>>>((const u16*)feat, flag);
    (void)hipMemsetAsync(cur3, 0, 3 * N_ * sizeof(int), stream);
    k_preC<<<PRE_TOT, 256, 0, stream>>>(flag, feat, featB,
                                        sl_w, sl_b, fus_w, fus_b, W1T, b1,
                                        rel_w, gate_w, va_w1, ft_w, la_w1,
                                        rel_b, gate_b, view_pref,
                                        va_b1, va_w2, va_b2,
                                        la_b1, la_w2, la_b2,
                                        pred_b, att_bias, ft_b, ln_g, ln_beta, pred_w,
                                        relT, gateT, vaT3, fus2T, ftT, laT, P,
                                        ei, cur3);
    k_scan_bsum<<<3 * NB_SCAN, 256, 0, stream>>>(cur3, bsum);
    k_scan_write<<<3 * NB_SCAN, 256, 0, stream>>>(cur3, bsum, offs3);
    k_place<<<3 * EGRID, 256, 0, stream>>>(flag, ei, ew, cur3, srcw3);
    k_fused<<<NBLK, 768, 0, stream>>>(flag, feat, featB, srcw3, offs3, cur3,
                                      relT, gateT, vaT3, W1T, fus2T, ftT, laT,
                                      b1, P, d_out);
}

// Round 8
// 517.505 us; speedup vs baseline: 1.1799x; 1.1154x over previous
//
#include <hip/hip_runtime.h>

#define N_ 100000
#define D_ 128
#define O_ 128
#define V_ 3
#define E_ 400000
#define NB_SCAN 98   // ceil(N/1024)
#define EGRID 1563   // ceil(E/256)
#define MB 32        // nodes per k_fused block (N divisible: no tail)
#define NBLK (N_ / MB)   // 3125
#define LDA 136      // padded bf16 row stride (16B-aligned)

// fused pre-kernel block ranges
#define PRE_CVT  6250                   // feature cvt (f32 path only)
#define PRE_PREW (PRE_CVT + 64)         // 6314
#define PRE_PREP (PRE_PREW + 683)       // 6997 (prep ids 174598 -> 683 blocks)
#define PRE_TOT  (PRE_PREP + 3 * EGRID) // 11686

typedef unsigned short u16;
typedef __attribute__((ext_vector_type(8))) short bf16x8;   // 8 bf16 = 4 VGPRs
typedef __attribute__((ext_vector_type(4))) float f32x4;

#define MFMA16x16x32 __builtin_amdgcn_mfma_f32_16x16x32_bf16

// ---- fp32 param block offsets (in workspace, filled by prep) ----
#define P_RELB  0
#define P_GATEB 384
#define P_VP    768
#define P_VAB1  1152
#define P_VAW2  1216
#define P_VAB2  1280
#define P_LAB1  1281
#define P_LAW2  1409
#define P_LAB2  1537
#define P_PREDB 1539
#define P_ATTB  1541
#define P_FTB   1542
#define P_LNG   1670
#define P_LNB   1798
#define P_PREDW 1926
#define P_TOTAL 2182

__device__ __forceinline__ float b2f(u16 u) {
    union { float f; unsigned int i; } x; x.i = ((unsigned int)u) << 16; return x.f;
}
__device__ __forceinline__ float blo(unsigned int u) {
    union { float f; unsigned int i; } x; x.i = u << 16; return x.f;
}
__device__ __forceinline__ float bhi(unsigned int u) {
    union { float f; unsigned int i; } x; x.i = u & 0xffff0000u; return x.f;
}
__device__ __forceinline__ u16 f2b(float f) {
    union { float f; unsigned int i; } x; x.f = f;
    unsigned int r = x.i + 0x7FFFu + ((x.i >> 16) & 1u);
    return (u16)(r >> 16);
}

template<int F32> __device__ __forceinline__ float LD(const void* p, size_t i) {
    if (F32) return ((const float*)p)[i];
    return b2f(((const u16*)p)[i]);
}

// ---------------- dtype detector: fp32 vs bf16 element stream ----------------
__global__ void k_detect(const u16* __restrict__ feat, int* __restrict__ flag) {
    int t = threadIdx.x;
    u16 a = feat[2 * t], b = feat[2 * t + 128];
    int zeros = (a == 0 ? 1 : 0) + (b == 0 ? 1 : 0);
    float va = b2f(a), vb = b2f(b);
    int bad = (!(va > -128.f && va < 128.f) ? 1 : 0) +
              (!(vb > -128.f && vb < 128.f) ? 1 : 0);
    #pragma unroll
    for (int s = 1; s <= 32; s <<= 1) {
        bad += __shfl_xor(bad, s);
        zeros += __shfl_xor(zeros, s);
    }
    if (t == 0) flag[0] = (bad >= 16 || zeros >= 64) ? 1 : 0;
}

// ---------------- fused pre kernel: cvt | prew | prep | count ----------------
__device__ __forceinline__ void cvt_body_f32(int b, const void* feat,
                                             u16* __restrict__ featB) {
    size_t idx = (size_t)b * 256 + threadIdx.x;   // 8 elems per thread
    const float4* fp = (const float4*)feat;
    float4 a = fp[idx * 2], c = fp[idx * 2 + 1];
    uint4 u;
    u.x = (unsigned)f2b(a.x) | ((unsigned)f2b(a.y) << 16);
    u.y = (unsigned)f2b(a.z) | ((unsigned)f2b(a.w) << 16);
    u.z = (unsigned)f2b(c.x) | ((unsigned)f2b(c.y) << 16);
    u.w = (unsigned)f2b(c.z) | ((unsigned)f2b(c.w) << 16);
    ((uint4*)featB)[idx] = u;
}

template<int F32>
__device__ __forceinline__ void prew_body(int b, const void* sl_w, const void* sl_b,
                                          const void* fus_w, const void* fus_b,
                                          u16* __restrict__ W1T, float* __restrict__ b1) {
    int gid = b * 256 + threadIdx.x;   // 64 blocks
    int d = gid >> 7, o = gid & 127;
    float acc = 0.f;
    for (int k = 0; k < 128; ++k)
        acc += LD<F32>(sl_w, d * 128 + k) * LD<F32>(fus_w, k * 128 + o);
    W1T[o * 128 + d] = f2b(acc);
    if (gid < 128) {
        float accb = 0.f;
        for (int k = 0; k < 128; ++k)
            accb += LD<F32>(sl_b, k) * LD<F32>(fus_w, k * 128 + gid);
        b1[gid] = accb + LD<F32>(fus_b, gid);
    }
}

// prep: bf16 transposed weights, fp32 P-block, fused RG = rel_w@gate_w
template<int F32>
__device__ __forceinline__ void prep_body(int b,
        const void* rel_w, const void* gate_w, const void* va_w1, const void* fus_w,
        const void* ft_w, const void* la_w1,
        const void* rel_b, const void* gate_b, const void* vpref,
        const void* va_b1, const void* va_w2, const void* va_b2,
        const void* la_b1, const void* la_w2, const void* la_b2,
        const void* pred_b, const void* att_bias, const void* ft_b,
        const void* ln_g, const void* ln_beta, const void* pred_w,
        u16* __restrict__ relT, u16* __restrict__ rgT, u16* __restrict__ vaT3,
        u16* __restrict__ fus2T, u16* __restrict__ ftT, u16* __restrict__ laT,
        float* __restrict__ P, float* __restrict__ rgb) {
    int id = b * 256 + threadIdx.x;
    if (id < 49152) {
        int v = id >> 14, r = id & 16383, o = r >> 7, d = r & 127;
        relT[id] = f2b(LD<F32>(rel_w, (size_t)v * 16384 + d * 128 + o));
    } else if (id < 73728) {
        // vaT3[v][n][k] = va_w1[k][n] * view_pref[v][k]
        int t = id - 49152, v = t >> 13, r = t & 8191, n = r >> 7, k = r & 127;
        vaT3[t] = f2b(LD<F32>(va_w1, k * 64 + n) * LD<F32>(vpref, v * 128 + k));
    } else if (id < 90112) {
        int t = id - 73728, n = t >> 7, k = t & 127;
        fus2T[t] = f2b(LD<F32>(fus_w, (128 + k) * 128 + n));
    } else if (id < 106496) {
        int t = id - 90112, o = t >> 7, d = t & 127;
        ftT[t] = f2b(LD<F32>(ft_w, d * 128 + o));
    } else if (id < 122880) {
        int t = id - 106496, n = t >> 7, d = t & 127;
        int c = n >> 6, j = n & 63;
        laT[t] = f2b(LD<F32>(la_w1, c * 8192 + d * 64 + j));
    } else if (id < 122880 + P_TOTAL) {
        int t = id - 122880;
        float val;
        if      (t < P_GATEB) val = LD<F32>(rel_b, t);
        else if (t < P_VP)    val = LD<F32>(gate_b, t - P_GATEB);
        else if (t < P_VAB1)  val = LD<F32>(vpref, t - P_VP);
        else if (t < P_VAW2)  val = LD<F32>(va_b1, t - P_VAB1);
        else if (t < P_VAB2)  val = LD<F32>(va_w2, t - P_VAW2);
        else if (t < P_LAB1)  val = LD<F32>(va_b2, 0);
        else if (t < P_LAW2)  val = LD<F32>(la_b1, t - P_LAB1);
        else if (t < P_LAB2)  val = LD<F32>(la_w2, t - P_LAW2);
        else if (t < P_PREDB) val = LD<F32>(la_b2, t - P_LAB2);
        else if (t < P_ATTB)  val = LD<F32>(pred_b, t - P_PREDB);
        else if (t < P_FTB)   val = LD<F32>(att_bias, 0);
        else if (t < P_LNG)   val = LD<F32>(ft_b, t - P_FTB);
        else if (t < P_LNB)   val = LD<F32>(ln_g, t - P_LNG);
        else if (t < P_PREDW) val = LD<F32>(ln_beta, t - P_LNB);
        else                  val = LD<F32>(pred_w, t - P_PREDW);
        P[t] = val;
    } else if (id < 174214) {
        // rgT[v][n][d] = sum_o rel_w[v][d][o] * gate_w[v][o][n]
        int t = id - 125062, v = t >> 14, r = t & 16383, n = r >> 7, d = r & 127;
        float acc = 0.f;
        for (int o = 0; o < 128; ++o)
            acc += LD<F32>(rel_w,  (size_t)v * 16384 + d * 128 + o) *
                   LD<F32>(gate_w, (size_t)v * 16384 + o * 128 + n);
        rgT[t] = f2b(acc);
    } else if (id < 174598) {
        // rgb[v][n] = sum_o rel_b[v][o] * gate_w[v][o][n]
        int t = id - 174214, v = t >> 7, n = t & 127;
        float acc = 0.f;
        for (int o = 0; o < 128; ++o)
            acc += LD<F32>(rel_b, v * 128 + o) *
                   LD<F32>(gate_w, (size_t)v * 16384 + o * 128 + n);
        rgb[t] = acc;
    }
}

__global__ __launch_bounds__(256) void k_preC(const int* __restrict__ flag,
        const void* feat, u16* __restrict__ featB,
        const void* sl_w, const void* sl_b, const void* fus_w, const void* fus_b,
        u16* __restrict__ W1T, float* __restrict__ b1,
        const void* rel_w, const void* gate_w, const void* va_w1,
        const void* ft_w, const void* la_w1,
        const void* rel_b, const void* gate_b, const void* vpref,
        const void* va_b1, const void* va_w2, const void* va_b2,
        const void* la_b1, const void* la_w2, const void* la_b2,
        const void* pred_b, const void* att_bias, const void* ft_b,
        const void* ln_g, const void* ln_beta, const void* pred_w,
        u16* __restrict__ relT, u16* __restrict__ rgT, u16* __restrict__ vaT3,
        u16* __restrict__ fus2T, u16* __restrict__ ftT, u16* __restrict__ laT,
        float* __restrict__ P, float* __restrict__ rgb,
        const int* __restrict__ ei, int* __restrict__ cur3) {
    int b = blockIdx.x;
    if (b < PRE_CVT) {
        if (flag[0]) cvt_body_f32(b, feat, featB);
    } else if (b < PRE_PREW) {
        if (flag[0]) prew_body<1>(b - PRE_CVT, sl_w, sl_b, fus_w, fus_b, W1T, b1);
        else         prew_body<0>(b - PRE_CVT, sl_w, sl_b, fus_w, fus_b, W1T, b1);
    } else if (b < PRE_PREP) {
        if (flag[0]) prep_body<1>(b - PRE_PREW, rel_w, gate_w, va_w1, fus_w, ft_w, la_w1,
                                  rel_b, gate_b, vpref, va_b1, va_w2, va_b2,
                                  la_b1, la_w2, la_b2, pred_b, att_bias, ft_b,
                                  ln_g, ln_beta, pred_w, relT, rgT, vaT3, fus2T, ftT, laT, P, rgb);
        else         prep_body<0>(b - PRE_PREW, rel_w, gate_w, va_w1, fus_w, ft_w, la_w1,
                                  rel_b, gate_b, vpref, va_b1, va_w2, va_b2,
                                  la_b1, la_w2, la_b2, pred_b, att_bias, ft_b,
                                  ln_g, ln_beta, pred_w, relT, rgT, vaT3, fus2T, ftT, laT, P, rgb);
    } else {
        int b2 = b - PRE_PREP;
        int v = b2 / EGRID;
        int e = (b2 % EGRID) * 256 + threadIdx.x;
        if (e < E_) atomicAdd(&cur3[v * N_ + ei[(size_t)v * 2 * E_ + E_ + e]], 1);
    }
}

// ---------------- CSR scan: bsum / write (inline spine) ----------------------
__global__ __launch_bounds__(256) void k_scan_bsum(const int* __restrict__ cur3,
                                                   int* __restrict__ bsum) {
    __shared__ int red[256];
    const int v = blockIdx.x / NB_SCAN, b = blockIdx.x % NB_SCAN, tid = threadIdx.x;
    const int base = b * 1024;
    const int* counts = cur3 + v * N_;
    int s = 0;
    for (int i = tid; i < 1024; i += 256) {
        int idx = base + i;
        s += (idx < N_) ? counts[idx] : 0;
    }
    red[tid] = s;
    __syncthreads();
    for (int st = 128; st >= 1; st >>= 1) {
        if (tid < st) red[tid] += red[tid + st];
        __syncthreads();
    }
    if (tid == 0) bsum[v * 128 + b] = red[0];
}

__global__ __launch_bounds__(256) void k_scan_write(int* __restrict__ cur3,
                                                    const int* __restrict__ bsum,
                                                    int* __restrict__ offs3) {
    __shared__ int lsum[256];
    __shared__ int bs_s[128];
    const int v = blockIdx.x / NB_SCAN, b = blockIdx.x % NB_SCAN, tid = threadIdx.x;
    const int base = b * 1024;
    int* counts = cur3 + v * N_;
    int* offs   = offs3 + v * N_;
    if (tid < 128) bs_s[tid] = (tid < b) ? bsum[v * 128 + tid] : 0;
    int c[4]; int s = 0;
    #pragma unroll
    for (int k = 0; k < 4; ++k) {
        int idx = base + tid * 4 + k;
        c[k] = (idx < N_) ? counts[idx] : 0;
        s += c[k];
    }
    lsum[tid] = s;
    __syncthreads();
    for (int st = 1; st < 256; st <<= 1) {
        int t = (tid >= st) ? lsum[tid - st] : 0;
        __syncthreads();
        lsum[tid] += t;
        __syncthreads();
    }
    for (int st = 64; st >= 1; st >>= 1) {
        if (tid < st) bs_s[tid] += bs_s[tid + st];
        __syncthreads();
    }
    int off = bs_s[0] + lsum[tid] - s;
    #pragma unroll
    for (int k = 0; k < 4; ++k) {
        int idx = base + tid * 4 + k;
        if (idx < N_) { offs[idx] = off; counts[idx] = off; }
        off += c[k];
    }
}

// place: srcw[pos] = {src, weight-bits}
template<int F32>
__device__ __forceinline__ void place_body(const int* __restrict__ ei, const void* ew_all,
                                           int* __restrict__ cur3, int2* __restrict__ srcw3) {
    int v = blockIdx.x / EGRID;
    int e = (blockIdx.x % EGRID) * 256 + threadIdx.x;
    if (e < E_) {
        int dst = ei[(size_t)v * 2 * E_ + E_ + e];
        int src = ei[(size_t)v * 2 * E_ + e];
        float w = LD<F32>(ew_all, (size_t)v * E_ + e);
        int pos = atomicAdd(&cur3[v * N_ + dst], 1);
        int2 sw; sw.x = src; sw.y = __float_as_int(w);
        srcw3[(size_t)v * E_ + pos] = sw;
    }
}
__global__ __launch_bounds__(256) void k_place(const int* __restrict__ flag,
                                               const int* __restrict__ ei, const void* ew,
                                               int* __restrict__ cur3, int2* __restrict__ srcw3) {
    if (flag[0]) place_body<1>(ei, ew, cur3, srcw3);
    else         place_body<0>(ei, ew, cur3, srcw3);
}

// ------ fused MFMA pipeline: MB=32, 768 threads, view-parallel groups --------
// Dual-B GEMM fuses rel+gate phases via precomputed RG = rel_w@gate_w:
// both agg and gate_in are GEMMs of z -> one phase, one A-load, no agg
// LDS round-trip. Barriers 12 -> 10.
__global__ __launch_bounds__(768, 6) void k_fused(const int* __restrict__ flag,
        const void* feat, const u16* __restrict__ featB_,
        const int2* __restrict__ srcw3,
        const int* __restrict__ offs3, const int* __restrict__ ends3,
        const u16* __restrict__ relT, const u16* __restrict__ rgT,
        const u16* __restrict__ vaT3, const u16* __restrict__ W1T,
        const u16* __restrict__ fus2T, const u16* __restrict__ ftT,
        const u16* __restrict__ laT,
        const float* __restrict__ b1, const float* __restrict__ rgb,
        const float* __restrict__ P,
        void* __restrict__ d_out) {
    const int f32 = flag[0];
    const u16* __restrict__ fb = f32 ? featB_ : (const u16*)feat;

    __shared__ __align__(16) u16 S[4 * MB * LDA];     // xA | zb0 | zb1 | zb2
    __shared__ float redL[4][MB];
    __shared__ float redv[3][4][MB];                  // va reduce; overlay LN red2
    __shared__ float wsn3[3][MB];
    __shared__ float aw_s[MB][3];
    __shared__ float natt_s[MB];
    __shared__ float lg_s[MB][2];
    __shared__ float mrs_s[MB][2];

    u16* xA = S;
    float* F1 = (float*)(S + 2 * MB * LDA);   // 16KB over zb1+zb2
    float* F2 = (float*)S;                    // 16KB over xA+zb0
    float* red2 = &redv[0][0][0];             // [4][MB][2] overlay (256 f32)

    const int tid = threadIdx.x;
    const int g   = tid >> 8;               // wave-group / view 0..2
    const int t256 = tid & 255;
    const int wid = t256 >> 6;              // wave within group 0..3
    const int L = t256 & 63, q = L >> 4, i = L & 15;
    const int nb = wid * 32;
    const int nodebase = blockIdx.x * MB;
    const int nl = t256 >> 5, l32 = t256 & 31, o4 = l32 * 4;
    const int gsub = t256 >> 4, l16 = tid & 15, o8 = l16 * 8;
    const f32x4 zz = {0.f, 0.f, 0.f, 0.f};
    u16* zc = S + (size_t)(1 + g) * MB * LDA;   // this group's z buffer

    auto ldf = [&](const u16* B, int row, int k0) -> bf16x8 {
        return *(const bf16x8*)&B[row * LDA + k0];
    };
    auto ldg = [&](const u16* B, int row, int k0) -> bf16x8 {
        return *(const bf16x8*)&B[row * 128 + k0];
    };
    // M=32 gemm by 4 waves of one group
    auto gemm32 = [&](const u16* A, const u16* Bg, f32x4 acc[2][2]) {
        #pragma unroll
        for (int kk = 0; kk < 4; ++kk) {
            int k0 = q * 8 + kk * 32;
            bf16x8 a0 = ldf(A, i, k0);
            bf16x8 a1 = ldf(A, i + 16, k0);
            bf16x8 bb0 = ldg(Bg, nb + i, k0);
            bf16x8 bb1 = ldg(Bg, nb + 16 + i, k0);
            acc[0][0] = MFMA16x16x32(a0, bb0, acc[0][0], 0, 0, 0);
            acc[0][1] = MFMA16x16x32(a0, bb1, acc[0][1], 0, 0, 0);
            acc[1][0] = MFMA16x16x32(a1, bb0, acc[1][0], 0, 0, 0);
            acc[1][1] = MFMA16x16x32(a1, bb1, acc[1][1], 0, 0, 0);
        }
    };
    // dual-B gemm: same A fragments feed two B matrices
    auto gemm32x2 = [&](const u16* A, const u16* B0g, const u16* B1g,
                        f32x4 accA[2][2], f32x4 accB[2][2]) {
        #pragma unroll
        for (int kk = 0; kk < 4; ++kk) {
            int k0 = q * 8 + kk * 32;
            bf16x8 a0 = ldf(A, i, k0);
            bf16x8 a1 = ldf(A, i + 16, k0);
            bf16x8 p0 = ldg(B0g, nb + i, k0);
            bf16x8 p1 = ldg(B0g, nb + 16 + i, k0);
            bf16x8 r0 = ldg(B1g, nb + i, k0);
            bf16x8 r1 = ldg(B1g, nb + 16 + i, k0);
            accA[0][0] = MFMA16x16x32(a0, p0, accA[0][0], 0, 0, 0);
            accA[0][1] = MFMA16x16x32(a0, p1, accA[0][1], 0, 0, 0);
            accA[1][0] = MFMA16x16x32(a1, p0, accA[1][0], 0, 0, 0);
            accA[1][1] = MFMA16x16x32(a1, p1, accA[1][1], 0, 0, 0);
            accB[0][0] = MFMA16x16x32(a0, r0, accB[0][0], 0, 0, 0);
            accB[0][1] = MFMA16x16x32(a0, r1, accB[0][1], 0, 0, 0);
            accB[1][0] = MFMA16x16x32(a1, r0, accB[1][0], 0, 0, 0);
            accB[1][1] = MFMA16x16x32(a1, r1, accB[1][1], 0, 0, 0);
        }
    };
    // gather view g: 16 subgroups of 16 lanes; nodes gsub and gsub+16
    auto gather = [&]() {
        const int* offs = offs3 + g * N_;
        const int* ends = ends3 + g * N_;
        const int2* srcw = srcw3 + (size_t)g * E_;
        #pragma unroll
        for (int rep = 0; rep < 2; ++rep) {
            const int m = gsub + rep * 16;
            const int node = nodebase + m;
            float z0 = 0.f, z1 = 0.f, z2 = 0.f, z3 = 0.f;
            float z4 = 0.f, z5 = 0.f, z6 = 0.f, z7 = 0.f, ws = 0.f;
            int j = offs[node], jend = ends[node];
            while (j < jend) {
                int r = jend - j;
                int2 e0 = srcw[j];
                int2 e1, e2, e3;
                e1.x = 0; e1.y = 0; e2.x = 0; e2.y = 0; e3.x = 0; e3.y = 0;
                if (r > 1) e1 = srcw[j + 1];
                if (r > 2) e2 = srcw[j + 2];
                if (r > 3) e3 = srcw[j + 3];
                uint4 x0, x1, x2, x3;
                x1.x = x1.y = x1.z = x1.w = 0;
                x2.x = x2.y = x2.z = x2.w = 0;
                x3.x = x3.y = x3.z = x3.w = 0;
                x0 = *(const uint4*)&fb[(size_t)e0.x * 128 + o8];
                if (r > 1) x1 = *(const uint4*)&fb[(size_t)e1.x * 128 + o8];
                if (r > 2) x2 = *(const uint4*)&fb[(size_t)e2.x * 128 + o8];
                if (r > 3) x3 = *(const uint4*)&fb[(size_t)e3.x * 128 + o8];
                float w0 = __int_as_float(e0.y), w1 = __int_as_float(e1.y);
                float w2 = __int_as_float(e2.y), w3 = __int_as_float(e3.y);
                ws += w0 + w1 + w2 + w3;
                z0 += w0 * blo(x0.x) + w1 * blo(x1.x) + w2 * blo(x2.x) + w3 * blo(x3.x);
                z1 += w0 * bhi(x0.x) + w1 * bhi(x1.x) + w2 * bhi(x2.x) + w3 * bhi(x3.x);
                z2 += w0 * blo(x0.y) + w1 * blo(x1.y) + w2 * blo(x2.y) + w3 * blo(x3.y);
                z3 += w0 * bhi(x0.y) + w1 * bhi(x1.y) + w2 * bhi(x2.y) + w3 * bhi(x3.y);
                z4 += w0 * blo(x0.z) + w1 * blo(x1.z) + w2 * blo(x2.z) + w3 * blo(x3.z);
                z5 += w0 * bhi(x0.z) + w1 * bhi(x1.z) + w2 * bhi(x2.z) + w3 * bhi(x3.z);
                z6 += w0 * blo(x0.w) + w1 * blo(x1.w) + w2 * blo(x2.w) + w3 * blo(x3.w);
                z7 += w0 * bhi(x0.w) + w1 * bhi(x1.w) + w2 * bhi(x2.w) + w3 * bhi(x3.w);
                j += 4;
            }
            uint4 u;
            u.x = (unsigned)f2b(z0) | ((unsigned)f2b(z1) << 16);
            u.y = (unsigned)f2b(z2) | ((unsigned)f2b(z3) << 16);
            u.z = (unsigned)f2b(z4) | ((unsigned)f2b(z5) << 16);
            u.w = (unsigned)f2b(z6) | ((unsigned)f2b(z7) << 16);
            *(uint4*)&zc[m * LDA + o8] = u;
            if (l16 == 0) wsn3[g][m] = ws;
        }
    };

    // ---- P0: stage xA; each group gathers its view ----
    if (tid < 512) {
        int m = tid >> 4, s = tid & 15;
        *(uint4*)&xA[m * LDA + s * 8] =
            *(const uint4*)&fb[(size_t)(nodebase + m) * 128 + s * 8];
    }
    gather();
    __syncthreads();                                               // B1

    // ---- P1: g1 la-gemm, g2 logits, ALL dual rel+rg gemm ----
    if (g == 1) {
        f32x4 accL[2][2] = {{zz, zz}, {zz, zz}};
        gemm32(xA, laT, accL);
        float la0 = P[P_LAB1 + nb + i],  la1 = P[P_LAB1 + nb + 16 + i];
        float lw0 = P[P_LAW2 + nb + i],  lw1 = P[P_LAW2 + nb + 16 + i];
        float partL[2][4];
        #pragma unroll
        for (int mt = 0; mt < 2; ++mt)
            #pragma unroll
            for (int r = 0; r < 4; ++r) {
                float h0 = fmaxf(accL[mt][0][r] + la0, 0.f);
                float h1 = fmaxf(accL[mt][1][r] + la1, 0.f);
                partL[mt][r] = h0 * lw0 + h1 * lw1;
            }
        #pragma unroll
        for (int s = 1; s <= 8; s <<= 1)
            #pragma unroll
            for (int mt = 0; mt < 2; ++mt)
                #pragma unroll
                for (int r = 0; r < 4; ++r)
                    partL[mt][r] += __shfl_xor(partL[mt][r], s);
        if (i == 0)
            #pragma unroll
            for (int mt = 0; mt < 2; ++mt)
                #pragma unroll
                for (int r = 0; r < 4; ++r)
                    redL[wid][mt * 16 + q * 4 + r] = partL[mt][r];
    }
    if (g == 2) {
        float pw[8];
        #pragma unroll
        for (int t = 0; t < 4; ++t) {
            pw[2 * t]     = P[P_PREDW + (o4 + t) * 2];
            pw[2 * t + 1] = P[P_PREDW + (o4 + t) * 2 + 1];
        }
        #pragma unroll
        for (int rep = 0; rep < 4; ++rep) {
            int m = rep * 8 + nl;
            float lg0 = 0.f, lg1 = 0.f;
            #pragma unroll
            for (int t = 0; t < 4; ++t) {
                float xv = b2f(xA[m * LDA + o4 + t]);
                lg0 += xv * pw[2 * t];
                lg1 += xv * pw[2 * t + 1];
            }
            #pragma unroll
            for (int s = 1; s <= 16; s <<= 1) {
                lg0 += __shfl_xor(lg0, s);
                lg1 += __shfl_xor(lg1, s);
            }
            if (l32 == 0) { lg_s[m][0] = lg0; lg_s[m][1] = lg1; }
        }
    }
    f32x4 accA[2][2] = {{zz, zz}, {zz, zz}};
    f32x4 accG[2][2] = {{zz, zz}, {zz, zz}};
    gemm32x2(zc, relT + (size_t)g * 16384, rgT + (size_t)g * 16384, accA, accG);
    __syncthreads();                                               // B2

    // ---- P2: vv = sigmoid(z@RG + wsn*rgb + gb) * (z@rel + wsn*rb) -> zc ----
    {
        float rb0 = P[P_RELB + g * 128 + nb + i];
        float rb1 = P[P_RELB + g * 128 + nb + 16 + i];
        float rg0 = rgb[g * 128 + nb + i];
        float rg1 = rgb[g * 128 + nb + 16 + i];
        float gb0 = P[P_GATEB + g * 128 + nb + i];
        float gb1 = P[P_GATEB + g * 128 + nb + 16 + i];
        #pragma unroll
        for (int mt = 0; mt < 2; ++mt)
            #pragma unroll
            for (int nt = 0; nt < 2; ++nt) {
                float rb = nt ? rb1 : rb0;
                float rg = nt ? rg1 : rg0;
                float gb = nt ? gb1 : gb0;
                int col = nb + nt * 16 + i;
                #pragma unroll
                for (int r = 0; r < 4; ++r) {
                    int row = mt * 16 + q * 4 + r;
                    float ws = wsn3[g][row];
                    float agg = accA[mt][nt][r] + ws * rb;
                    float gin = accG[mt][nt][r] + ws * rg + gb;
                    float gt = 1.f / (1.f + __expf(-gin));
                    zc[row * LDA + col] = f2b(gt * agg);
                }
            }
    }
    if (tid < MB) {
        float c0 = redL[0][tid] + redL[1][tid] + P[P_LAB2 + 0];
        float c1 = redL[2][tid] + redL[3][tid] + P[P_LAB2 + 1];
        float s0 = 1.f / (1.f + __expf(-c0));
        float s1 = 1.f / (1.f + __expf(-c1));
        float l0 = lg_s[tid][0] + P[P_PREDB + 0];
        float l1 = lg_s[tid][1] + P[P_PREDB + 1];
        float mx = fmaxf(l0, l1);
        float e0 = __expf(l0 - mx), e1 = __expf(l1 - mx);
        float inv = 1.f / (e0 + e1);
        float p0 = e0 * inv, p1 = e1 * inv;
        natt_s[tid] = s0 * p0 + s1 * p1 + P[P_ATTB];
        int node = nodebase + tid;
        if (f32) {
            float* pr = (float*)d_out + (size_t)N_ * O_;
            pr[node * 2 + 0] = p0; pr[node * 2 + 1] = p1;
        } else {
            u16* pr = (u16*)d_out + (size_t)N_ * O_;
            pr[node * 2 + 0] = f2b(p0); pr[node * 2 + 1] = f2b(p1);
        }
    }
    __syncthreads();                                               // B3

    // ---- P3: va gemm on vv (vaT3 has vp folded) ----
    {
        f32x4 accV[2] = {zz, zz};
        const int nbv = wid * 16, colv = nbv + i;
        const u16* vaW = vaT3 + (size_t)g * 8192;
        #pragma unroll
        for (int kk = 0; kk < 4; ++kk) {
            int k0 = q * 8 + kk * 32;
            bf16x8 bb = ldg(vaW, nbv + i, k0);
            bf16x8 a0 = ldf(zc, i, k0);
            bf16x8 a1 = ldf(zc, i + 16, k0);
            accV[0] = MFMA16x16x32(a0, bb, accV[0], 0, 0, 0);
            accV[1] = MFMA16x16x32(a1, bb, accV[1], 0, 0, 0);
        }
        float vb1v = P[P_VAB1 + colv], vw2v = P[P_VAW2 + colv];
        float part[2][4];
        #pragma unroll
        for (int mt = 0; mt < 2; ++mt)
            #pragma unroll
            for (int r = 0; r < 4; ++r) {
                float vh = fmaxf(accV[mt][r] + vb1v, 0.f);
                part[mt][r] = vh * vw2v;
            }
        #pragma unroll
        for (int s = 1; s <= 8; s <<= 1)
            #pragma unroll
            for (int mt = 0; mt < 2; ++mt)
                #pragma unroll
                for (int r = 0; r < 4; ++r)
                    part[mt][r] += __shfl_xor(part[mt][r], s);
        if (i == 0)
            #pragma unroll
            for (int mt = 0; mt < 2; ++mt)
                #pragma unroll
                for (int r = 0; r < 4; ++r)
                    redv[g][wid][mt * 16 + q * 4 + r] = part[mt][r];
    }
    __syncthreads();                                               // B4

    // ---- P4: vscore + view softmax * natt (tid<32) ----
    if (tid < MB) {
        float sv[3];
        #pragma unroll
        for (int v = 0; v < 3; ++v)
            sv[v] = redv[v][0][tid] + redv[v][1][tid] +
                    redv[v][2][tid] + redv[v][3][tid] + P[P_VAB2];
        float mx = fmaxf(sv[0], fmaxf(sv[1], sv[2]));
        float e0 = __expf(sv[0] - mx), e1 = __expf(sv[1] - mx), e2 = __expf(sv[2] - mx);
        float inv = natt_s[tid] / (e0 + e1 + e2);
        aw_s[tid][0] = e0 * inv; aw_s[tid][1] = e1 * inv; aw_s[tid][2] = e2 * inv;
    }
    __syncthreads();                                               // B5

    // ---- P5: combine wt = sum_v aw_v*vv_v -> zb0 (lane-owned) ----
    {
        u16* z0p = S + MB * LDA;
        u16* z1p = S + 2 * MB * LDA;
        u16* z2p = S + 3 * MB * LDA;
        for (int idx = tid; idx < MB * 128; idx += 768) {
            int row = idx >> 7, col = idx & 127;
            float w = aw_s[row][0] * b2f(z0p[row * LDA + col]) +
                      aw_s[row][1] * b2f(z1p[row * LDA + col]) +
                      aw_s[row][2] * b2f(z2p[row * LDA + col]);
            z0p[row * LDA + col] = f2b(w);
        }
    }
    __syncthreads();                                               // B6

    // ---- P6: fusion gemms, one per group ----
    f32x4 accF[2][2] = {{zz, zz}, {zz, zz}};
    if (g == 0) {
        gemm32(xA, W1T, accF);
        #pragma unroll
        for (int mt = 0; mt < 2; ++mt)
            #pragma unroll
            for (int nt = 0; nt < 2; ++nt)
                #pragma unroll
                for (int r = 0; r < 4; ++r)
                    F1[(mt * 16 + q * 4 + r) * 128 + nb + nt * 16 + i] = accF[mt][nt][r];
    } else if (g == 1) {
        gemm32(S + MB * LDA, fus2T, accF);   // wt @ fus_w[128:]
    } else {
        gemm32(xA, ftT, accF);               // accT kept in regs
    }
    __syncthreads();                                               // B7
    if (g == 1) {                            // xA+zb0 dead -> write F2
        #pragma unroll
        for (int mt = 0; mt < 2; ++mt)
            #pragma unroll
            for (int nt = 0; nt < 2; ++nt)
                #pragma unroll
                for (int r = 0; r < 4; ++r)
                    F2[(mt * 16 + q * 4 + r) * 128 + nb + nt * 16 + i] = accF[mt][nt][r];
    }
    __syncthreads();                                               // B7b

    // ---- P7: g2: out = relu(F1+F2+b1) + accT + ftb -> F1; LN partials ----
    if (g == 2) {
        float b1v0 = b1[nb + i], b1v1 = b1[nb + 16 + i];
        float fb0 = P[P_FTB + nb + i], fb1 = P[P_FTB + nb + 16 + i];
        float ps[2][4], pq[2][4];
        #pragma unroll
        for (int mt = 0; mt < 2; ++mt)
            #pragma unroll
            for (int r = 0; r < 4; ++r) { ps[mt][r] = 0.f; pq[mt][r] = 0.f; }
        #pragma unroll
        for (int mt = 0; mt < 2; ++mt)
            #pragma unroll
            for (int nt = 0; nt < 2; ++nt) {
                int col = nb + nt * 16 + i;
                float bv = nt ? b1v1 : b1v0;
                float fv = nt ? fb1 : fb0;
                #pragma unroll
                for (int r = 0; r < 4; ++r) {
                    int rc = (mt * 16 + q * 4 + r) * 128 + col;
                    float o = fmaxf(F1[rc] + F2[rc] + bv, 0.f) + accF[mt][nt][r] + fv;
                    F1[rc] = o;
                    ps[mt][r] += o; pq[mt][r] += o * o;
                }
            }
        #pragma unroll
        for (int s = 1; s <= 8; s <<= 1)
            #pragma unroll
            for (int mt = 0; mt < 2; ++mt)
                #pragma unroll
                for (int r = 0; r < 4; ++r) {
                    ps[mt][r] += __shfl_xor(ps[mt][r], s);
                    pq[mt][r] += __shfl_xor(pq[mt][r], s);
                }
        if (i == 0)
            #pragma unroll
            for (int mt = 0; mt < 2; ++mt)
                #pragma unroll
                for (int r = 0; r < 4; ++r) {
                    int row = mt * 16 + q * 4 + r;
                    red2[(wid * MB + row) * 2 + 0] = ps[mt][r];
                    red2[(wid * MB + row) * 2 + 1] = pq[mt][r];
                }
    }
    __syncthreads();                                               // B8

    // ---- P8: LN stats (tid<32) ----
    if (tid < MB) {
        float sm = red2[tid * 2]            + red2[(MB + tid) * 2] +
                   red2[(2 * MB + tid) * 2] + red2[(3 * MB + tid) * 2];
        float sq = red2[tid * 2 + 1]            + red2[(MB + tid) * 2 + 1] +
                   red2[(2 * MB + tid) * 2 + 1] + red2[(3 * MB + tid) * 2 + 1];
        float mu = sm * (1.f / 128.f);
        float var = sq * (1.f / 128.f) - mu * mu;
        mrs_s[tid][0] = mu; mrs_s[tid][1] = rsqrtf(var + 1e-5f);
    }
    __syncthreads();                                               // B9

    // ---- P9: normalize from F1 and store (all 768 threads) ----
    if (f32) {
        float* op = (float*)d_out + (size_t)nodebase * 128;
        for (int idx = tid; idx < MB * 128; idx += 768) {
            int row = idx >> 7, col = idx & 127;
            op[idx] = (F1[idx] - mrs_s[row][0]) * mrs_s[row][1]
                      * P[P_LNG + col] + P[P_LNB + col];
        }
    } else {
        unsigned* op = (unsigned*)d_out + (size_t)nodebase * 64;
        for (int idx = tid; idx < MB * 64; idx += 768) {
            int row = idx >> 6, c2 = (idx & 63) * 2;
            float m0 = mrs_s[row][0], r0 = mrs_s[row][1];
            float v0 = (F1[row * 128 + c2]     - m0) * r0 * P[P_LNG + c2]     + P[P_LNB + c2];
            float v1 = (F1[row * 128 + c2 + 1] - m0) * r0 * P[P_LNG + c2 + 1] + P[P_LNB + c2 + 1];
            op[idx] = (unsigned)f2b(v0) | ((unsigned)f2b(v1) << 16);
        }
    }
}

extern "C" void kernel_launch(void* const* d_in, const int* in_sizes, int n_in,
                              void* d_out, int out_size, void* d_ws, size_t ws_size,
                              hipStream_t stream) {
    const void* feat     = d_in[0];
    const int*  ei       = (const int*)d_in[1];
    const void* ew       = d_in[2];
    const void* rel_w    = d_in[3];
    const void* rel_b    = d_in[4];
    const void* gate_w   = d_in[5];
    const void* gate_b   = d_in[6];
    const void* la_w1    = d_in[7];
    const void* la_b1    = d_in[8];
    const void* la_w2    = d_in[9];
    const void* la_b2    = d_in[10];
    const void* pred_w   = d_in[11];
    const void* pred_b   = d_in[12];
    const void* att_bias = d_in[13];
    const void* view_pref= d_in[14];
    const void* va_w1    = d_in[15];
    const void* va_b1    = d_in[16];
    const void* va_w2    = d_in[17];
    const void* va_b2    = d_in[18];
    const void* ft_w     = d_in[19];
    const void* ft_b     = d_in[20];
    const void* sl_w     = d_in[21];
    const void* sl_b     = d_in[22];
    const void* fus_w    = d_in[23];
    const void* fus_b    = d_in[24];
    const void* ln_g     = d_in[25];
    const void* ln_beta  = d_in[26];

    // workspace layout (~38 MB total)
    int*   flag  = (int*)d_ws;                    // 4 ints
    int*   offs3 = flag + 4;                      // 3N
    int*   cur3  = offs3 + 3 * N_;                // 3N
    int2*  srcw3 = (int2*)(cur3 + 3 * N_);        // 3E int2 (16B-aligned)
    int*   bsum  = (int*)(srcw3 + 3 * E_);        // 3*128
    float* b1    = (float*)(bsum + 3 * 128);      // 128
    float* P     = b1 + 128;                      // 2182 (pad to 2304)
    float* rgb   = P + 2304;                      // 384
    u16*   W1T   = (u16*)(rgb + 384);             // 16384
    u16*   relT  = W1T + 16384;                   // 3*16384
    u16*   rgT   = relT + 3 * 16384;              // 3*16384 (rel_w@gate_w)^T
    u16*   vaT3  = rgT + 3 * 16384;               // 3*8192 (vp folded)
    u16*   fus2T = vaT3 + 3 * 8192;               // 16384
    u16*   ftT   = fus2T + 16384;                 // 16384
    u16*   laT   = ftT + 16384;                   // 16384
    u16*   featB = laT + 16384;                   // N*128 bf16 (f32 input case)

    k_detect<<<1, 64, 0, stream>>>((const u16*)feat, flag);
    (void)hipMemsetAsync(cur3, 0, 3 * N_ * sizeof(int), stream);
    k_preC<<<PRE_TOT, 256, 0, stream>>>(flag, feat, featB,
                                        sl_w, sl_b, fus_w, fus_b, W1T, b1,
                                        rel_w, gate_w, va_w1, ft_w, la_w1,
                                        rel_b, gate_b, view_pref,
                                        va_b1, va_w2, va_b2,
                                        la_b1, la_w2, la_b2,
                                        pred_b, att_bias, ft_b, ln_g, ln_beta, pred_w,
                                        relT, rgT, vaT3, fus2T, ftT, laT, P, rgb,
                                        ei, cur3);
    k_scan_bsum<<<3 * NB_SCAN, 256, 0, stream>>>(cur3, bsum);
    k_scan_write<<<3 * NB_SCAN, 256, 0, stream>>>(cur3, bsum, offs3);
    k_place<<<3 * EGRID, 256, 0, stream>>>(flag, ei, ew, cur3, srcw3);
    k_fused<<<NBLK, 768, 0, stream>>>(flag, feat, featB, srcw3, offs3, cur3,
                                      relT, rgT, vaT3, W1T, fus2T, ftT, laT,
                                      b1, rgb, P, d_out);
}